// Round 6
// baseline (178.204 us; speedup 1.0000x reference)
//
#include <hip/hip_runtime.h>
#include <cstdint>
#include <cstddef>

#define N_TOK 4096
#define CQ    256
#define CK    32

typedef __attribute__((ext_vector_type(4))) float  f32x4;
typedef __attribute__((ext_vector_type(8))) __bf16 bf16x8;
typedef __attribute__((ext_vector_type(4))) short  s16x4;

__device__ __forceinline__ unsigned short f2bf(float f) {
  union { float f; unsigned u; } x; x.f = f;
  unsigned r = x.u + 0x7FFFu + ((x.u >> 16) & 1u);   // RNE
  return (unsigned short)(r >> 16);
}

__device__ __forceinline__ f32x4 mfma16(bf16x8 a, bf16x8 b, f32x4 c) {
  return __builtin_amdgcn_mfma_f32_16x16x32_bf16(a, b, c, 0, 0, 0);
}

// ---------------------------------------------------------------------------
// Prep: weight folds + xk bf16 prep, merged by blockIdx range. Grid 128 x 256.
// ---------------------------------------------------------------------------
__global__ __launch_bounds__(256) void prep_kernel(
    const float* __restrict__ Wq, const float* __restrict__ bq,
    const float* __restrict__ Wk, const float* __restrict__ Wv,
    const float* __restrict__ bv, const float* __restrict__ Wo,
    const float* __restrict__ bo, const float* __restrict__ Fk,
    unsigned short* __restrict__ Aqkt, float* __restrict__ bqk,
    unsigned short* __restrict__ W2bf, float* __restrict__ c2,
    unsigned short* __restrict__ xkb, unsigned short* __restrict__ XkT)
{
  __shared__ float red[256];
  __shared__ unsigned short trs[128][33];
  const int blk = blockIdx.x, t = threadIdx.x;
  if (blk < 32) {
    const int j = blk;
    float acc = 0.f;
    #pragma unroll 8
    for (int i = 0; i < CQ; i++)
      acc = fmaf(Wq[(size_t)i * CQ + t], Wk[(size_t)i * CK + j], acc);
    Aqkt[(size_t)j * CQ + t] = f2bf(0.125f * acc);
    red[t] = bq[t] * Wk[(size_t)t * CK + j];
    __syncthreads();
    for (int s = 128; s > 0; s >>= 1) {
      if (t < s) red[t] += red[t + s];
      __syncthreads();
    }
    if (t == 0) bqk[j] = 0.125f * red[0];
  } else if (blk < 64) {
    const int j = blk - 32;
    float acc = 0.f, acc2 = 0.f;
    #pragma unroll 8
    for (int i = 0; i < CQ; i++) {
      float wo = Wo[(size_t)t * CQ + i];
      acc  = fmaf(wo, Wv[(size_t)i * CK + j], acc);
      acc2 = fmaf(wo, bv[i], acc2);
    }
    W2bf[(size_t)t * CK + j] = f2bf(acc);
    if (j == 0) c2[t] = bo[t] + acc2;
  } else {
    const int blk2 = blk - 64;
    const int b = blk2 >> 5;
    const int t0 = (blk2 & 31) << 7;
    #pragma unroll
    for (int i = 0; i < 4; i++) {
      int flat = (i * 256 + t) << 2;            // over [32 ch][128 tok]
      int r = flat >> 7, c4 = flat & 127;
      float4 v = *(const float4*)(Fk + ((size_t)(b * CK + r)) * N_TOK + t0 + c4);
      ushort4 u = { f2bf(v.x), f2bf(v.y), f2bf(v.z), f2bf(v.w) };
      *(ushort4*)(xkb + ((size_t)(b * CK + r)) * N_TOK + t0 + c4) = u;
      trs[c4][r] = u.x; trs[c4+1][r] = u.y; trs[c4+2][r] = u.z; trs[c4+3][r] = u.w;
    }
    __syncthreads();
    const int token = t >> 1, half = t & 1;
    unsigned short tmp[16] __attribute__((aligned(16)));
    #pragma unroll
    for (int k = 0; k < 16; k++) tmp[k] = trs[token][half * 16 + k];
    unsigned short* dst = XkT + ((size_t)(b * N_TOK + t0 + token)) * CK + half * 16;
    ((uint4*)dst)[0] = ((const uint4*)tmp)[0];
    ((uint4*)dst)[1] = ((const uint4*)tmp)[1];
  }
}

// ---------------------------------------------------------------------------
// Q'' projection: QN[b][tok][32] = bf16( xq . Aqk + bqk )  (SCALE folded)
// grid 256 (b x 128 token-tiles of 32) x 128 thr (2 waves of 16 tokens).
// ---------------------------------------------------------------------------
__global__ __launch_bounds__(128) void qproj_kernel(
    const float* __restrict__ X, const unsigned short* __restrict__ Aqkt,
    const float* __restrict__ bqk, unsigned short* __restrict__ QN)
{
  __shared__ unsigned short bs[32][40];
  const int b = blockIdx.x >> 7;
  const int t0 = (blockIdx.x & 127) << 5;
  const int t = threadIdx.x, w = t >> 6;
  const int lane = t & 63, c = lane & 15, g = lane >> 4;
  f32x4 acc[2] = {};
  for (int k0 = 0; k0 < CQ; k0 += 32) {
    #pragma unroll
    for (int i = 0; i < 2; i++) {            // stage X [32c][32tok] -> bs[tok][c]
      int flat = (i * 128 + t) << 2;
      int cc = flat >> 5, tk = flat & 31;
      float4 v = *(const float4*)(X + ((size_t)(b * CQ + k0 + cc)) * N_TOK + t0 + tk);
      bs[tk  ][cc] = f2bf(v.x); bs[tk+1][cc] = f2bf(v.y);
      bs[tk+2][cc] = f2bf(v.z); bs[tk+3][cc] = f2bf(v.w);
    }
    __syncthreads();
    bf16x8 a = *(const bf16x8*)&bs[w * 16 + c][g * 8];
    #pragma unroll
    for (int nt = 0; nt < 2; nt++) {
      bf16x8 bB = *(const bf16x8*)(Aqkt + (size_t)(nt * 16 + c) * CQ + k0 + g * 8);
      acc[nt] = mfma16(a, bB, acc[nt]);
    }
    __syncthreads();
  }
  #pragma unroll
  for (int nt = 0; nt < 2; nt++) {
    float bj = bqk[nt * 16 + c];
    #pragma unroll
    for (int r = 0; r < 4; r++)
      QN[((size_t)(b * N_TOK + t0 + w * 16 + g * 4 + r)) * CK + nt * 16 + c] =
          f2bf(acc[nt][r] + bj);
  }
}

// ---------------------------------------------------------------------------
// Flash, S^T formulation, flat softmax. Grid 2048 = (b, qtile(256), ksp(4)),
// 256 thr (4 waves). Wave owns 256 keys: 16 indep S^T MFMAs (A=XkT, B=QN ->
// col=token), in-lane max/sum + 2 shuffles, P^T stays in registers. PV uses
// the verified 16x16x32 MFMA with a GLOBAL slot permutation pi applied
// identically to A (V^T) and B (P^T): slot g*8+j <-> key g*4+j (j<4) /
// 16+g*4+(j-4) (j>=4). r5 postmortem: PV was correct; the bug was the
// partML epilogue using token (t>>3)'s mM while indexing token t -- fixed
// by recomputing the per-token max inside the t<16 branch.
// ---------------------------------------------------------------------------
__global__ __launch_bounds__(256) void flash_kernel(
    const unsigned short* __restrict__ QN, const unsigned short* __restrict__ XkT,
    const unsigned short* __restrict__ xkb, float* __restrict__ partO,
    float* __restrict__ partML)
{
  __shared__ float om[4][32][17];
  __shared__ float ml[4][2][16];
  const int blk = blockIdx.x;
  const int b   = blk >> 10;
  const int qt  = (blk >> 2) & 255;
  const int ksp = blk & 3;
  const int t = threadIdx.x, w = t >> 6;
  const int lane = t & 63, c = lane & 15, g = lane >> 4;
  const int t0 = qt * 16;
  const int kbase = ksp * 1024 + w * 256;

  // Q'' B-frag: B[k=ch g*8+j][n=tok c]
  const bf16x8 qf = *(const bf16x8*)(QN + ((size_t)(b * N_TOK + t0 + c)) * CK + g * 8);

  // ---- phase 1: S^T for all 256 keys (16 independent MFMAs) ----
  f32x4 s[4][4];
  #pragma unroll
  for (int it = 0; it < 4; it++)
    #pragma unroll
    for (int nt = 0; nt < 4; nt++) {
      const int k0 = kbase + it * 64 + nt * 16;
      bf16x8 ak = *(const bf16x8*)(XkT + ((size_t)(b * N_TOK + k0 + c)) * CK + g * 8);
      f32x4 z = {};
      s[it][nt] = mfma16(ak, qf, z);      // row=key(g*4+r), col=token(c)
    }

  // ---- phase 2: per-token max (in-lane 64 values + 2 shuffle rounds) ----
  float mx = -1e30f;
  #pragma unroll
  for (int it = 0; it < 4; it++)
    #pragma unroll
    for (int nt = 0; nt < 4; nt++)
      mx = fmaxf(mx, fmaxf(fmaxf(s[it][nt][0], s[it][nt][1]),
                           fmaxf(s[it][nt][2], s[it][nt][3])));
  mx = fmaxf(mx, __shfl_xor(mx, 16));
  mx = fmaxf(mx, __shfl_xor(mx, 32));

  // ---- phase 3: exp, sum, pack P^T (register-resident) ----
  float l = 0.f;
  s16x4 pf[4][4];
  #pragma unroll
  for (int it = 0; it < 4; it++)
    #pragma unroll
    for (int nt = 0; nt < 4; nt++) {
      float p0 = __expf(s[it][nt][0] - mx);
      float p1 = __expf(s[it][nt][1] - mx);
      float p2 = __expf(s[it][nt][2] - mx);
      float p3 = __expf(s[it][nt][3] - mx);
      l += (p0 + p1) + (p2 + p3);
      s16x4 p;
      p[0] = (short)f2bf(p0); p[1] = (short)f2bf(p1);
      p[2] = (short)f2bf(p2); p[3] = (short)f2bf(p3);
      pf[it][nt] = p;
    }
  l += __shfl_xor(l, 16);
  l += __shfl_xor(l, 32);

  // ---- phase 4: O^T = V^T P^T (16 independent K=32 MFMAs, paired chunks) ----
  f32x4 o0 = {}, o1 = {};
  const unsigned short* vb0 = xkb + ((size_t)(b * CK + c))      * N_TOK;
  const unsigned short* vb1 = xkb + ((size_t)(b * CK + 16 + c)) * N_TOK;
  #pragma unroll
  for (int it = 0; it < 4; it++)
    #pragma unroll
    for (int ntp = 0; ntp < 2; ntp++) {
      const int k0 = kbase + it * 64 + ntp * 32 + g * 4;
      union { s16x4 h[2]; bf16x8 v; } bu, a0u, a1u;
      bu.h[0]  = pf[it][ntp * 2];
      bu.h[1]  = pf[it][ntp * 2 + 1];
      a0u.h[0] = *(const s16x4*)(vb0 + k0);
      a0u.h[1] = *(const s16x4*)(vb0 + k0 + 16);
      a1u.h[0] = *(const s16x4*)(vb1 + k0);
      a1u.h[1] = *(const s16x4*)(vb1 + k0 + 16);
      o0 = mfma16(a0u.v, bu.v, o0);       // row=d(g*4+r), col=token(c)
      o1 = mfma16(a1u.v, bu.v, o1);
    }

  // ---- 4-wave LDS merge -> block partial ----
  #pragma unroll
  for (int r = 0; r < 4; r++) {
    om[w][g * 4 + r][c]      = o0[r];
    om[w][16 + g * 4 + r][c] = o1[r];
  }
  if (lane < 16) { ml[w][0][lane] = mx; ml[w][1][lane] = l; }
  __syncthreads();
  if (t < 128) {
    const int tok = t >> 3, c0 = (t & 7) * 4;
    float mM = fmaxf(fmaxf(ml[0][0][tok], ml[1][0][tok]),
                     fmaxf(ml[2][0][tok], ml[3][0][tok]));
    float f[4];
    #pragma unroll
    for (int w4 = 0; w4 < 4; w4++) f[w4] = __expf(ml[w4][0][tok] - mM);
    float v[4] = {};
    #pragma unroll
    for (int w4 = 0; w4 < 4; w4++)
      #pragma unroll
      for (int i = 0; i < 4; i++)
        v[i] = fmaf(f[w4], om[w4][c0 + i][tok], v[i]);
    float4 out = { v[0], v[1], v[2], v[3] };
    *(float4*)(partO + (size_t)blk * 512 + tok * 32 + c0) = out;
    if (t < 16) {
      // FIX (r5 bug): recompute the per-token max for token t -- the
      // enclosing-scope mM belongs to token t>>3.
      float mT = fmaxf(fmaxf(ml[0][0][t], ml[1][0][t]),
                       fmaxf(ml[2][0][t], ml[3][0][t]));
      float lsum = 0.f;
      #pragma unroll
      for (int w4 = 0; w4 < 4; w4++)
        lsum = fmaf(__expf(ml[w4][0][t] - mT), ml[w4][1][t], lsum);
      partML[(size_t)blk * 32 + t]      = mT;
      partML[(size_t)blk * 32 + 16 + t] = lsum;
    }
  }
}

// ---------------------------------------------------------------------------
// Merge 4 ksplit block-partials -> ON[b][tok][32] bf16 normalized.
// grid 256 x 256; thread = (b, qtile, tok, 4-chan group).
// ---------------------------------------------------------------------------
__global__ __launch_bounds__(256) void merge_kernel(
    const float* __restrict__ partO, const float* __restrict__ partML,
    unsigned short* __restrict__ ON)
{
  const int gt = blockIdx.x * 256 + threadIdx.x;   // 65536 total
  const int ch4 = gt & 7, tok = (gt >> 3) & 15;
  const int qt = (gt >> 7) & 255, b = gt >> 15;
  const int blkbase = ((b << 8) + qt) << 2;
  float mv[4], lv[4], mM = -1e30f;
  #pragma unroll
  for (int k = 0; k < 4; k++) {
    mv[k] = partML[(size_t)(blkbase + k) * 32 + tok];
    lv[k] = partML[(size_t)(blkbase + k) * 32 + 16 + tok];
    mM = fmaxf(mM, mv[k]);
  }
  float lsum = 0.f, f[4];
  #pragma unroll
  for (int k = 0; k < 4; k++) {
    f[k] = __expf(mv[k] - mM);
    lsum = fmaf(f[k], lv[k], lsum);
  }
  const float inv = 1.0f / lsum;
  float acc[4] = {};
  #pragma unroll
  for (int k = 0; k < 4; k++) {
    float4 v = *(const float4*)(partO + (size_t)(blkbase + k) * 512 + tok * 32 + ch4 * 4);
    acc[0] = fmaf(f[k], v.x, acc[0]); acc[1] = fmaf(f[k], v.y, acc[1]);
    acc[2] = fmaf(f[k], v.z, acc[2]); acc[3] = fmaf(f[k], v.w, acc[3]);
  }
  ushort4 u = { f2bf(acc[0] * inv), f2bf(acc[1] * inv),
                f2bf(acc[2] * inv), f2bf(acc[3] * inv) };
  *(ushort4*)(ON + ((size_t)(b * N_TOK + qt * 16 + tok)) * CK + ch4 * 4) = u;
}

// ---------------------------------------------------------------------------
// Output projection + residual: Y[b][o][t] = ON . W2^T + c2 + X.
// Grid 128 (b x 4 og x 16 tt) x 256 thr (4 waves of 16 o-rows).
// ---------------------------------------------------------------------------
__global__ __launch_bounds__(256) void oproj_kernel(
    const unsigned short* __restrict__ ON, const unsigned short* __restrict__ W2bf,
    const float* __restrict__ c2, const float* __restrict__ X,
    float* __restrict__ Y)
{
  const int blk = blockIdx.x;
  const int b  = blk >> 6;
  const int og = (blk >> 4) & 3;
  const int tt = blk & 15;
  const int t = threadIdx.x, w = t >> 6;
  const int lane = t & 63, c = lane & 15, g = lane >> 4;
  const int m0 = og * 64 + w * 16;
  const int t0 = tt * 256;
  bf16x8 aW = *(const bf16x8*)(W2bf + (size_t)(m0 + c) * CK + g * 8);
  f32x4 acc[16] = {};
  #pragma unroll
  for (int nt = 0; nt < 16; nt++) {
    bf16x8 bB = *(const bf16x8*)(ON + ((size_t)(b * N_TOK + t0 + nt * 16 + c)) * CK + g * 8);
    acc[nt] = mfma16(aW, bB, acc[nt]);
  }
  float cc2[4];
  #pragma unroll
  for (int r = 0; r < 4; r++) cc2[r] = c2[m0 + g * 4 + r];
  #pragma unroll
  for (int nt = 0; nt < 16; nt++)
    #pragma unroll
    for (int r = 0; r < 4; r++) {
      size_t idx = ((size_t)(b * CQ + m0 + g * 4 + r)) * N_TOK + t0 + nt * 16 + c;
      Y[idx] = acc[nt][r] + cc2[r] + X[idx];
    }
}

// ---------------------------------------------------------------------------
extern "C" void kernel_launch(void* const* d_in, const int* in_sizes, int n_in,
                              void* d_out, int out_size, void* d_ws, size_t ws_size,
                              hipStream_t stream) {
  const float* F  = (const float*)d_in[0];   // [2,256,4096]
  const float* Fk = (const float*)d_in[1];   // [2,32,4096]
  const float* Wq = (const float*)d_in[2];
  const float* bq = (const float*)d_in[3];
  const float* Wk = (const float*)d_in[4];
  // bk (d_in[5]) is provably softmax-invariant -> dropped
  const float* Wv = (const float*)d_in[6];
  const float* bv = (const float*)d_in[7];
  const float* Wo = (const float*)d_in[8];
  const float* bo = (const float*)d_in[9];
  float* Y = (float*)d_out;
  char* ws = (char*)d_ws;
  unsigned short* XkT   = (unsigned short*)(ws);                 // 512 KB [2,4096,32]
  unsigned short* xkb   = (unsigned short*)(ws + (512u << 10));  // 512 KB [2,32,4096]
  unsigned short* ON    = (unsigned short*)(ws + (1024u << 10)); // 512 KB [2,4096,32]
  unsigned short* QN    = (unsigned short*)(ws + (1536u << 10)); // 512 KB [2,4096,32]
  unsigned short* Aqkt  = (unsigned short*)(ws + (2048u << 10)); // 16 KB  [32,256]
  unsigned short* W2bf  = (unsigned short*)(ws + (2080u << 10)); // 16 KB  [256,32]
  float*          bqk   = (float*)(ws + (2112u << 10));          // 128 B
  float*          c2    = (float*)(ws + (2116u << 10));          // 1 KB
  float*          partO = (float*)(ws + (4096u << 10));          // 4 MB  [2048][512]
  float*          partML= (float*)(ws + (8192u << 10));          // 256 KB [2048][32]

  prep_kernel <<<128,  256, 0, stream>>>(Wq, bq, Wk, Wv, bv, Wo, bo, Fk,
                                         Aqkt, bqk, W2bf, c2, xkb, XkT);
  qproj_kernel<<<256,  128, 0, stream>>>(F, Aqkt, bqk, QN);
  flash_kernel<<<2048, 256, 0, stream>>>(QN, XkT, xkb, partO, partML);
  merge_kernel<<<256,  256, 0, stream>>>(partO, partML, ON);
  oproj_kernel<<<128,  256, 0, stream>>>(ON, W2bf, c2, F, Y);
}

// Round 7
// 175.890 us; speedup vs baseline: 1.0132x; 1.0132x over previous
//
#include <hip/hip_runtime.h>
#include <cstdint>
#include <cstddef>

#define N_TOK 4096
#define CQ    256
#define CK    32

typedef __attribute__((ext_vector_type(4))) float  f32x4;
typedef __attribute__((ext_vector_type(8))) __bf16 bf16x8;
typedef __attribute__((ext_vector_type(4))) short  s16x4;

__device__ __forceinline__ unsigned short f2bf(float f) {
  union { float f; unsigned u; } x; x.f = f;
  unsigned r = x.u + 0x7FFFu + ((x.u >> 16) & 1u);   // RNE
  return (unsigned short)(r >> 16);
}

__device__ __forceinline__ f32x4 mfma16(bf16x8 a, bf16x8 b, f32x4 c) {
  return __builtin_amdgcn_mfma_f32_16x16x32_bf16(a, b, c, 0, 0, 0);
}

// ---------------------------------------------------------------------------
// Prep: weight folds + xk bf16 prep, merged by blockIdx range. Grid 128 x 256.
// ---------------------------------------------------------------------------
__global__ __launch_bounds__(256) void prep_kernel(
    const float* __restrict__ Wq, const float* __restrict__ bq,
    const float* __restrict__ Wk, const float* __restrict__ Wv,
    const float* __restrict__ bv, const float* __restrict__ Wo,
    const float* __restrict__ bo, const float* __restrict__ Fk,
    unsigned short* __restrict__ Aqkt, float* __restrict__ bqk,
    unsigned short* __restrict__ W2bf, float* __restrict__ c2,
    unsigned short* __restrict__ xkb, unsigned short* __restrict__ XkT)
{
  __shared__ float red[256];
  __shared__ unsigned short trs[128][33];
  const int blk = blockIdx.x, t = threadIdx.x;
  if (blk < 32) {
    const int j = blk;
    float acc = 0.f;
    #pragma unroll 8
    for (int i = 0; i < CQ; i++)
      acc = fmaf(Wq[(size_t)i * CQ + t], Wk[(size_t)i * CK + j], acc);
    Aqkt[(size_t)j * CQ + t] = f2bf(0.125f * acc);
    red[t] = bq[t] * Wk[(size_t)t * CK + j];
    __syncthreads();
    for (int s = 128; s > 0; s >>= 1) {
      if (t < s) red[t] += red[t + s];
      __syncthreads();
    }
    if (t == 0) bqk[j] = 0.125f * red[0];
  } else if (blk < 64) {
    const int j = blk - 32;
    float acc = 0.f, acc2 = 0.f;
    #pragma unroll 8
    for (int i = 0; i < CQ; i++) {
      float wo = Wo[(size_t)t * CQ + i];
      acc  = fmaf(wo, Wv[(size_t)i * CK + j], acc);
      acc2 = fmaf(wo, bv[i], acc2);
    }
    W2bf[(size_t)t * CK + j] = f2bf(acc);
    if (j == 0) c2[t] = bo[t] + acc2;
  } else {
    const int blk2 = blk - 64;
    const int b = blk2 >> 5;
    const int t0 = (blk2 & 31) << 7;
    #pragma unroll
    for (int i = 0; i < 4; i++) {
      int flat = (i * 256 + t) << 2;            // over [32 ch][128 tok]
      int r = flat >> 7, c4 = flat & 127;
      float4 v = *(const float4*)(Fk + ((size_t)(b * CK + r)) * N_TOK + t0 + c4);
      ushort4 u = { f2bf(v.x), f2bf(v.y), f2bf(v.z), f2bf(v.w) };
      *(ushort4*)(xkb + ((size_t)(b * CK + r)) * N_TOK + t0 + c4) = u;
      trs[c4][r] = u.x; trs[c4+1][r] = u.y; trs[c4+2][r] = u.z; trs[c4+3][r] = u.w;
    }
    __syncthreads();
    const int token = t >> 1, half = t & 1;
    unsigned short tmp[16] __attribute__((aligned(16)));
    #pragma unroll
    for (int k = 0; k < 16; k++) tmp[k] = trs[token][half * 16 + k];
    unsigned short* dst = XkT + ((size_t)(b * N_TOK + t0 + token)) * CK + half * 16;
    ((uint4*)dst)[0] = ((const uint4*)tmp)[0];
    ((uint4*)dst)[1] = ((const uint4*)tmp)[1];
  }
}

// ---------------------------------------------------------------------------
// Q'' projection: QN[b][tok][32] = bf16( xq . Aqk + bqk )  (SCALE folded)
// grid 256 (b x 128 token-tiles of 32) x 128 thr (2 waves of 16 tokens).
// ---------------------------------------------------------------------------
__global__ __launch_bounds__(128) void qproj_kernel(
    const float* __restrict__ X, const unsigned short* __restrict__ Aqkt,
    const float* __restrict__ bqk, unsigned short* __restrict__ QN)
{
  __shared__ unsigned short bs[32][40];
  const int b = blockIdx.x >> 7;
  const int t0 = (blockIdx.x & 127) << 5;
  const int t = threadIdx.x, w = t >> 6;
  const int lane = t & 63, c = lane & 15, g = lane >> 4;
  f32x4 acc[2] = {};
  for (int k0 = 0; k0 < CQ; k0 += 32) {
    #pragma unroll
    for (int i = 0; i < 2; i++) {            // stage X [32c][32tok] -> bs[tok][c]
      int flat = (i * 128 + t) << 2;
      int cc = flat >> 5, tk = flat & 31;
      float4 v = *(const float4*)(X + ((size_t)(b * CQ + k0 + cc)) * N_TOK + t0 + tk);
      bs[tk  ][cc] = f2bf(v.x); bs[tk+1][cc] = f2bf(v.y);
      bs[tk+2][cc] = f2bf(v.z); bs[tk+3][cc] = f2bf(v.w);
    }
    __syncthreads();
    bf16x8 a = *(const bf16x8*)&bs[w * 16 + c][g * 8];
    #pragma unroll
    for (int nt = 0; nt < 2; nt++) {
      bf16x8 bB = *(const bf16x8*)(Aqkt + (size_t)(nt * 16 + c) * CQ + k0 + g * 8);
      acc[nt] = mfma16(a, bB, acc[nt]);
    }
    __syncthreads();
  }
  #pragma unroll
  for (int nt = 0; nt < 2; nt++) {
    float bj = bqk[nt * 16 + c];
    #pragma unroll
    for (int r = 0; r < 4; r++)
      QN[((size_t)(b * N_TOK + t0 + w * 16 + g * 4 + r)) * CK + nt * 16 + c] =
          f2bf(acc[nt][r] + bj);
  }
}

// ---------------------------------------------------------------------------
// Flash with LDS-staged K. Grid 2048 = (b, qg(128 of 32 tok), ksp(8 of 512
// keys)) x 256 thr. Block stages its contiguous 32KB XkT slice into LDS once
// (80B/key stride: S^T b128 reads are 2-way-bank = free). Wave (w01=token
// half, w23=key half): 16 tokens x 256 keys, flat softmax (r6-verified
// pipeline), S^T frags from LDS, PV V-frags from global xkb (verified paired-
// chunk permutation). Key-halves merge in-LDS; ksp=8 merged globally.
// ---------------------------------------------------------------------------
__global__ __launch_bounds__(256) void flash_kernel(
    const unsigned short* __restrict__ QN, const unsigned short* __restrict__ XkT,
    const unsigned short* __restrict__ xkb, float* __restrict__ partO,
    float* __restrict__ partML)
{
  __shared__ unsigned short ks[512 * 40] __attribute__((aligned(16)));  // 40 KB
  __shared__ float om[4][32][17];
  __shared__ float ml[4][2][16];
  const int blk = blockIdx.x;
  const int b   = blk >> 10;
  const int qg  = (blk >> 3) & 127;
  const int ksp = blk & 7;
  const int t = threadIdx.x, w = t >> 6;
  const int lane = t & 63, c = lane & 15, g = lane >> 4;
  const int w01 = w & 1, w23 = w >> 1;
  const int t0 = qg * 32 + w01 * 16;
  const int gk0 = ksp * 512;

  // ---- cooperative stage: XkT[b][gk0 .. gk0+512)[32] -> ks (stride 40 sh) ----
  {
    const unsigned short* src = XkT + ((size_t)(b * N_TOK + gk0)) * CK;
    #pragma unroll
    for (int r = 0; r < 8; r++) {
      int flat = r * 256 + t;                  // 16B units over 32KB
      int row = flat >> 2, part = flat & 3;
      *(uint4*)(ks + row * 40 + part * 8) = *(const uint4*)(src + (size_t)flat * 8);
    }
  }
  const bf16x8 qf = *(const bf16x8*)(QN + ((size_t)(b * N_TOK + t0 + c)) * CK + g * 8);
  __syncthreads();

  const int lkb = w23 * 256;                   // wave's key base within LDS

  // ---- phase 1: S^T for 256 keys (16 independent MFMAs, frags from LDS) ----
  f32x4 s[4][4];
  #pragma unroll
  for (int it = 0; it < 4; it++)
    #pragma unroll
    for (int nt = 0; nt < 4; nt++) {
      bf16x8 ak = *(const bf16x8*)&ks[(lkb + it * 64 + nt * 16 + c) * 40 + g * 8];
      f32x4 z = {};
      s[it][nt] = mfma16(ak, qf, z);           // row=key(g*4+r), col=token(c)
    }

  // ---- phase 2: per-token max ----
  float mx = -1e30f;
  #pragma unroll
  for (int it = 0; it < 4; it++)
    #pragma unroll
    for (int nt = 0; nt < 4; nt++)
      mx = fmaxf(mx, fmaxf(fmaxf(s[it][nt][0], s[it][nt][1]),
                           fmaxf(s[it][nt][2], s[it][nt][3])));
  mx = fmaxf(mx, __shfl_xor(mx, 16));
  mx = fmaxf(mx, __shfl_xor(mx, 32));

  // ---- phase 3: exp, sum, pack P^T (register-resident) ----
  float l = 0.f;
  s16x4 pf[4][4];
  #pragma unroll
  for (int it = 0; it < 4; it++)
    #pragma unroll
    for (int nt = 0; nt < 4; nt++) {
      float p0 = __expf(s[it][nt][0] - mx);
      float p1 = __expf(s[it][nt][1] - mx);
      float p2 = __expf(s[it][nt][2] - mx);
      float p3 = __expf(s[it][nt][3] - mx);
      l += (p0 + p1) + (p2 + p3);
      s16x4 p;
      p[0] = (short)f2bf(p0); p[1] = (short)f2bf(p1);
      p[2] = (short)f2bf(p2); p[3] = (short)f2bf(p3);
      pf[it][nt] = p;
    }
  l += __shfl_xor(l, 16);
  l += __shfl_xor(l, 32);

  // ---- phase 4: O^T = V^T P^T (16 K=32 MFMAs, paired-chunk permutation) ----
  f32x4 o0 = {}, o1 = {};
  const unsigned short* vb0 = xkb + ((size_t)(b * CK + c))      * N_TOK;
  const unsigned short* vb1 = xkb + ((size_t)(b * CK + 16 + c)) * N_TOK;
  #pragma unroll
  for (int it = 0; it < 4; it++)
    #pragma unroll
    for (int ntp = 0; ntp < 2; ntp++) {
      const int k0 = gk0 + lkb + it * 64 + ntp * 32 + g * 4;
      union { s16x4 h[2]; bf16x8 v; } bu, a0u, a1u;
      bu.h[0]  = pf[it][ntp * 2];
      bu.h[1]  = pf[it][ntp * 2 + 1];
      a0u.h[0] = *(const s16x4*)(vb0 + k0);
      a0u.h[1] = *(const s16x4*)(vb0 + k0 + 16);
      a1u.h[0] = *(const s16x4*)(vb1 + k0);
      a1u.h[1] = *(const s16x4*)(vb1 + k0 + 16);
      o0 = mfma16(a0u.v, bu.v, o0);            // row=d(g*4+r), col=token(c)
      o1 = mfma16(a1u.v, bu.v, o1);
    }

  // ---- in-LDS merge of the 2 key-halves per token-half ----
  #pragma unroll
  for (int r = 0; r < 4; r++) {
    om[w][g * 4 + r][c]      = o0[r];
    om[w][16 + g * 4 + r][c] = o1[r];
  }
  if (lane < 16) { ml[w][0][lane] = mx; ml[w][1][lane] = l; }
  __syncthreads();
  {
    // 256 threads: h = token half, tok (16), c0 = d-group of 4.
    const int h = t >> 7, tok = (t >> 3) & 15, c0 = (t & 7) * 4;
    const int wA = h, wB = h + 2;
    float mA = ml[wA][0][tok], mB = ml[wB][0][tok];
    float mM = fmaxf(mA, mB);
    float fA = __expf(mA - mM), fB = __expf(mB - mM);
    float v[4];
    #pragma unroll
    for (int i = 0; i < 4; i++)
      v[i] = fA * om[wA][c0 + i][tok] + fB * om[wB][c0 + i][tok];
    float4 out = { v[0], v[1], v[2], v[3] };
    *(float4*)(partO + (size_t)blk * 1024 + (h * 16 + tok) * 32 + c0) = out;
    if (t < 32) {
      const int h2 = t >> 4, tk2 = t & 15;
      float mA2 = ml[h2][0][tk2], mB2 = ml[h2 + 2][0][tk2];
      float mT = fmaxf(mA2, mB2);
      float lsum = __expf(mA2 - mT) * ml[h2][1][tk2] +
                   __expf(mB2 - mT) * ml[h2 + 2][1][tk2];
      partML[(size_t)blk * 64 + h2 * 16 + tk2]      = mT;
      partML[(size_t)blk * 64 + 32 + h2 * 16 + tk2] = lsum;
    }
  }
}

// ---------------------------------------------------------------------------
// Merge 8 ksplit block-partials -> ON[b][tok][32] bf16 normalized.
// grid 256 x 256; thread = (b, qg, tok32, 4-chan group of 8).
// ---------------------------------------------------------------------------
__global__ __launch_bounds__(256) void merge_kernel(
    const float* __restrict__ partO, const float* __restrict__ partML,
    unsigned short* __restrict__ ON)
{
  const int gt = blockIdx.x * 256 + threadIdx.x;   // 65536 total
  const int ch4 = gt & 7, tok = (gt >> 3) & 31;
  const int qg = (gt >> 8) & 127, b = gt >> 15;
  const int blkbase = ((b << 7) + qg) << 3;
  float mv[8], lv[8], mM = -1e30f;
  #pragma unroll
  for (int k = 0; k < 8; k++) {
    mv[k] = partML[(size_t)(blkbase + k) * 64 + tok];
    lv[k] = partML[(size_t)(blkbase + k) * 64 + 32 + tok];
    mM = fmaxf(mM, mv[k]);
  }
  float lsum = 0.f, f[8];
  #pragma unroll
  for (int k = 0; k < 8; k++) {
    f[k] = __expf(mv[k] - mM);
    lsum = fmaf(f[k], lv[k], lsum);
  }
  const float inv = 1.0f / lsum;
  float acc[4] = {};
  #pragma unroll
  for (int k = 0; k < 8; k++) {
    float4 v = *(const float4*)(partO + (size_t)(blkbase + k) * 1024 + tok * 32 + ch4 * 4);
    acc[0] = fmaf(f[k], v.x, acc[0]); acc[1] = fmaf(f[k], v.y, acc[1]);
    acc[2] = fmaf(f[k], v.z, acc[2]); acc[3] = fmaf(f[k], v.w, acc[3]);
  }
  ushort4 u = { f2bf(acc[0] * inv), f2bf(acc[1] * inv),
                f2bf(acc[2] * inv), f2bf(acc[3] * inv) };
  *(ushort4*)(ON + ((size_t)(b * N_TOK + qg * 32 + tok)) * CK + ch4 * 4) = u;
}

// ---------------------------------------------------------------------------
// Output projection + residual: Y[b][o][t] = ON . W2^T + c2 + X.
// Grid 128 (b x 4 og x 16 tt) x 256 thr (4 waves of 16 o-rows).
// ---------------------------------------------------------------------------
__global__ __launch_bounds__(256) void oproj_kernel(
    const unsigned short* __restrict__ ON, const unsigned short* __restrict__ W2bf,
    const float* __restrict__ c2, const float* __restrict__ X,
    float* __restrict__ Y)
{
  const int blk = blockIdx.x;
  const int b  = blk >> 6;
  const int og = (blk >> 4) & 3;
  const int tt = blk & 15;
  const int t = threadIdx.x, w = t >> 6;
  const int lane = t & 63, c = lane & 15, g = lane >> 4;
  const int m0 = og * 64 + w * 16;
  const int t0 = tt * 256;
  bf16x8 aW = *(const bf16x8*)(W2bf + (size_t)(m0 + c) * CK + g * 8);
  f32x4 acc[16] = {};
  #pragma unroll
  for (int nt = 0; nt < 16; nt++) {
    bf16x8 bB = *(const bf16x8*)(ON + ((size_t)(b * N_TOK + t0 + nt * 16 + c)) * CK + g * 8);
    acc[nt] = mfma16(aW, bB, acc[nt]);
  }
  float cc2[4];
  #pragma unroll
  for (int r = 0; r < 4; r++) cc2[r] = c2[m0 + g * 4 + r];
  #pragma unroll
  for (int nt = 0; nt < 16; nt++)
    #pragma unroll
    for (int r = 0; r < 4; r++) {
      size_t idx = ((size_t)(b * CQ + m0 + g * 4 + r)) * N_TOK + t0 + nt * 16 + c;
      Y[idx] = acc[nt][r] + cc2[r] + X[idx];
    }
}

// ---------------------------------------------------------------------------
extern "C" void kernel_launch(void* const* d_in, const int* in_sizes, int n_in,
                              void* d_out, int out_size, void* d_ws, size_t ws_size,
                              hipStream_t stream) {
  const float* F  = (const float*)d_in[0];   // [2,256,4096]
  const float* Fk = (const float*)d_in[1];   // [2,32,4096]
  const float* Wq = (const float*)d_in[2];
  const float* bq = (const float*)d_in[3];
  const float* Wk = (const float*)d_in[4];
  // bk (d_in[5]) is provably softmax-invariant -> dropped
  const float* Wv = (const float*)d_in[6];
  const float* bv = (const float*)d_in[7];
  const float* Wo = (const float*)d_in[8];
  const float* bo = (const float*)d_in[9];
  float* Y = (float*)d_out;
  char* ws = (char*)d_ws;
  unsigned short* XkT   = (unsigned short*)(ws);                 // 512 KB [2,4096,32]
  unsigned short* xkb   = (unsigned short*)(ws + (512u << 10));  // 512 KB [2,32,4096]
  unsigned short* ON    = (unsigned short*)(ws + (1024u << 10)); // 512 KB [2,4096,32]
  unsigned short* QN    = (unsigned short*)(ws + (1536u << 10)); // 512 KB [2,4096,32]
  unsigned short* Aqkt  = (unsigned short*)(ws + (2048u << 10)); // 16 KB  [32,256]
  unsigned short* W2bf  = (unsigned short*)(ws + (2080u << 10)); // 16 KB  [256,32]
  float*          bqk   = (float*)(ws + (2112u << 10));          // 128 B
  float*          c2    = (float*)(ws + (2116u << 10));          // 1 KB
  float*          partO = (float*)(ws + (4096u << 10));          // 8 MB  [2048][1024]
  float*          partML= (float*)(ws + (12288u << 10));         // 512 KB [2048][64]

  prep_kernel <<<128,  256, 0, stream>>>(Wq, bq, Wk, Wv, bv, Wo, bo, Fk,
                                         Aqkt, bqk, W2bf, c2, xkb, XkT);
  qproj_kernel<<<256,  128, 0, stream>>>(F, Aqkt, bqk, QN);
  flash_kernel<<<2048, 256, 0, stream>>>(QN, XkT, xkb, partO, partML);
  merge_kernel<<<256,  256, 0, stream>>>(partO, partML, ON);
  oproj_kernel<<<128,  256, 0, stream>>>(ON, W2bf, c2, F, Y);
}

// Round 8
// 152.239 us; speedup vs baseline: 1.1706x; 1.1554x over previous
//
#include <hip/hip_runtime.h>
#include <hip/hip_bf16.h>
#include <cstdint>
#include <cstddef>

#define N_TOK 4096
#define CQ    256
#define CK    32

typedef __attribute__((ext_vector_type(4))) float  f32x4;
typedef __attribute__((ext_vector_type(8))) __bf16 bf16x8;
typedef __attribute__((ext_vector_type(4))) short  s16x4;

__device__ __forceinline__ unsigned short f2bf(float f) {
  union { float f; unsigned u; } x; x.f = f;
  unsigned r = x.u + 0x7FFFu + ((x.u >> 16) & 1u);   // RNE
  return (unsigned short)(r >> 16);
}

__device__ __forceinline__ f32x4 mfma16(bf16x8 a, bf16x8 b, f32x4 c) {
  return __builtin_amdgcn_mfma_f32_16x16x32_bf16(a, b, c, 0, 0, 0);
}

// ---------------------------------------------------------------------------
// Prep: weight folds + xk bf16 prep. Grid 128 x 256.
//  blk 64..127: XkT[b][tok][ch] (QK A-frags, LDS-staged by flash) and
//               Vpv[b][key/4][d=32][4] -- the PV A-fragment tiling, so flash's
//               V loads are coalesced (8 lines/wave-load instead of 64).
// ---------------------------------------------------------------------------
__global__ __launch_bounds__(256) void prep_kernel(
    const float* __restrict__ Wq, const float* __restrict__ bq,
    const float* __restrict__ Wk, const float* __restrict__ Wv,
    const float* __restrict__ bv, const float* __restrict__ Wo,
    const float* __restrict__ bo, const float* __restrict__ Fk,
    unsigned short* __restrict__ Aqkt, float* __restrict__ bqk,
    unsigned short* __restrict__ W2bf, float* __restrict__ c2,
    unsigned short* __restrict__ Vpv, unsigned short* __restrict__ XkT)
{
  __shared__ float red[256];
  __shared__ unsigned short trs[128][33];
  const int blk = blockIdx.x, t = threadIdx.x;
  if (blk < 32) {
    const int j = blk;
    float acc = 0.f;
    #pragma unroll 8
    for (int i = 0; i < CQ; i++)
      acc = fmaf(Wq[(size_t)i * CQ + t], Wk[(size_t)i * CK + j], acc);
    Aqkt[(size_t)j * CQ + t] = f2bf(0.125f * acc);
    red[t] = bq[t] * Wk[(size_t)t * CK + j];
    __syncthreads();
    for (int s = 128; s > 0; s >>= 1) {
      if (t < s) red[t] += red[t + s];
      __syncthreads();
    }
    if (t == 0) bqk[j] = 0.125f * red[0];
  } else if (blk < 64) {
    const int j = blk - 32;
    float acc = 0.f, acc2 = 0.f;
    #pragma unroll 8
    for (int i = 0; i < CQ; i++) {
      float wo = Wo[(size_t)t * CQ + i];
      acc  = fmaf(wo, Wv[(size_t)i * CK + j], acc);
      acc2 = fmaf(wo, bv[i], acc2);
    }
    W2bf[(size_t)t * CK + j] = f2bf(acc);
    if (j == 0) c2[t] = bo[t] + acc2;
  } else {
    const int blk2 = blk - 64;
    const int b = blk2 >> 5;
    const int t0 = (blk2 & 31) << 7;
    #pragma unroll
    for (int i = 0; i < 4; i++) {
      int flat = (i * 256 + t) << 2;            // over [32 ch][128 tok]
      int r = flat >> 7, c4 = flat & 127;
      float4 v = *(const float4*)(Fk + ((size_t)(b * CK + r)) * N_TOK + t0 + c4);
      ushort4 u = { f2bf(v.x), f2bf(v.y), f2bf(v.z), f2bf(v.w) };
      trs[c4][r] = u.x; trs[c4+1][r] = u.y; trs[c4+2][r] = u.z; trs[c4+3][r] = u.w;
    }
    __syncthreads();
    {   // XkT: token-major (coalesced 32B/thread)
      const int token = t >> 1, half = t & 1;
      unsigned short tmp[16] __attribute__((aligned(16)));
      #pragma unroll
      for (int k = 0; k < 16; k++) tmp[k] = trs[token][half * 16 + k];
      unsigned short* dst = XkT + ((size_t)(b * N_TOK + t0 + token)) * CK + half * 16;
      ((uint4*)dst)[0] = ((const uint4*)tmp)[0];
      ((uint4*)dst)[1] = ((const uint4*)tmp)[1];
    }
    {   // Vpv[kg][d][dk]: PV A-frag tiling (coalesced 32B/thread)
      const int kgl = t >> 3, d0 = (t & 7) * 4;
      unsigned short tmp[16] __attribute__((aligned(16)));
      #pragma unroll
      for (int di = 0; di < 4; di++)
        #pragma unroll
        for (int dk = 0; dk < 4; dk++)
          tmp[di * 4 + dk] = trs[kgl * 4 + dk][d0 + di];
      unsigned short* dst = Vpv +
          (((size_t)b * 1024 + (t0 >> 2) + kgl) * CK + d0) * 4;
      ((uint4*)dst)[0] = ((const uint4*)tmp)[0];
      ((uint4*)dst)[1] = ((const uint4*)tmp)[1];
    }
  }
}

// ---------------------------------------------------------------------------
// Q'' projection: QN[b][tok][32] = bf16( xq . Aqk + bqk )  (SCALE folded)
// grid 256 (b x 128 token-tiles of 32) x 128 thr (2 waves of 16 tokens).
// ---------------------------------------------------------------------------
__global__ __launch_bounds__(128) void qproj_kernel(
    const float* __restrict__ X, const unsigned short* __restrict__ Aqkt,
    const float* __restrict__ bqk, unsigned short* __restrict__ QN)
{
  __shared__ unsigned short bs[32][40];
  const int b = blockIdx.x >> 7;
  const int t0 = (blockIdx.x & 127) << 5;
  const int t = threadIdx.x, w = t >> 6;
  const int lane = t & 63, c = lane & 15, g = lane >> 4;
  f32x4 acc[2] = {};
  for (int k0 = 0; k0 < CQ; k0 += 32) {
    #pragma unroll
    for (int i = 0; i < 2; i++) {            // stage X [32c][32tok] -> bs[tok][c]
      int flat = (i * 128 + t) << 2;
      int cc = flat >> 5, tk = flat & 31;
      float4 v = *(const float4*)(X + ((size_t)(b * CQ + k0 + cc)) * N_TOK + t0 + tk);
      bs[tk  ][cc] = f2bf(v.x); bs[tk+1][cc] = f2bf(v.y);
      bs[tk+2][cc] = f2bf(v.z); bs[tk+3][cc] = f2bf(v.w);
    }
    __syncthreads();
    bf16x8 a = *(const bf16x8*)&bs[w * 16 + c][g * 8];
    #pragma unroll
    for (int nt = 0; nt < 2; nt++) {
      bf16x8 bB = *(const bf16x8*)(Aqkt + (size_t)(nt * 16 + c) * CQ + k0 + g * 8);
      acc[nt] = mfma16(a, bB, acc[nt]);
    }
    __syncthreads();
  }
  #pragma unroll
  for (int nt = 0; nt < 2; nt++) {
    float bj = bqk[nt * 16 + c];
    #pragma unroll
    for (int r = 0; r < 4; r++)
      QN[((size_t)(b * N_TOK + t0 + w * 16 + g * 4 + r)) * CK + nt * 16 + c] =
          f2bf(acc[nt][r] + bj);
  }
}

// ---------------------------------------------------------------------------
// Flash. Grid 2048 = (b, qg(128 of 32 tok), ksp(8 of 512 keys)) x 256 thr.
// K staged in LDS (r7); V read from Vpv (PV-frag-major layout -> coalesced,
// r7 postmortem: the per-lane 8KB-stride xkb loads were 64-line scatters and
// the real ~30us limiter). Flat softmax; P^T register-resident with the
// verified paired-chunk slot permutation.
// ---------------------------------------------------------------------------
__global__ __launch_bounds__(256) void flash_kernel(
    const unsigned short* __restrict__ QN, const unsigned short* __restrict__ XkT,
    const unsigned short* __restrict__ Vpv, float* __restrict__ partO,
    float* __restrict__ partML)
{
  __shared__ unsigned short ks[512 * 40] __attribute__((aligned(16)));  // 40 KB
  __shared__ float om[4][32][17];
  __shared__ float ml[4][2][16];
  const int blk = blockIdx.x;
  const int b   = blk >> 10;
  const int qg  = (blk >> 3) & 127;
  const int ksp = blk & 7;
  const int t = threadIdx.x, w = t >> 6;
  const int lane = t & 63, c = lane & 15, g = lane >> 4;
  const int w01 = w & 1, w23 = w >> 1;
  const int t0 = qg * 32 + w01 * 16;
  const int gk0 = ksp * 512;

  // ---- cooperative stage: XkT[b][gk0 .. gk0+512)[32] -> ks (stride 40 sh) ----
  {
    const unsigned short* src = XkT + ((size_t)(b * N_TOK + gk0)) * CK;
    #pragma unroll
    for (int r = 0; r < 8; r++) {
      int flat = r * 256 + t;                  // 16B units over 32KB
      int row = flat >> 2, part = flat & 3;
      *(uint4*)(ks + row * 40 + part * 8) = *(const uint4*)(src + (size_t)flat * 8);
    }
  }
  const bf16x8 qf = *(const bf16x8*)(QN + ((size_t)(b * N_TOK + t0 + c)) * CK + g * 8);
  __syncthreads();

  const int lkb = w23 * 256;                   // wave's key base within LDS

  // ---- phase 1: S^T for 256 keys (16 independent MFMAs, frags from LDS) ----
  f32x4 s[4][4];
  #pragma unroll
  for (int it = 0; it < 4; it++)
    #pragma unroll
    for (int nt = 0; nt < 4; nt++) {
      bf16x8 ak = *(const bf16x8*)&ks[(lkb + it * 64 + nt * 16 + c) * 40 + g * 8];
      f32x4 z = {};
      s[it][nt] = mfma16(ak, qf, z);           // row=key(g*4+r), col=token(c)
    }

  // ---- phase 2: per-token max ----
  float mx = -1e30f;
  #pragma unroll
  for (int it = 0; it < 4; it++)
    #pragma unroll
    for (int nt = 0; nt < 4; nt++)
      mx = fmaxf(mx, fmaxf(fmaxf(s[it][nt][0], s[it][nt][1]),
                           fmaxf(s[it][nt][2], s[it][nt][3])));
  mx = fmaxf(mx, __shfl_xor(mx, 16));
  mx = fmaxf(mx, __shfl_xor(mx, 32));

  // ---- phase 3: exp, sum, pack P^T (packed cvt, register-resident) ----
  float l = 0.f;
  s16x4 pf[4][4];
  #pragma unroll
  for (int it = 0; it < 4; it++)
    #pragma unroll
    for (int nt = 0; nt < 4; nt++) {
      float p0 = __expf(s[it][nt][0] - mx);
      float p1 = __expf(s[it][nt][1] - mx);
      float p2 = __expf(s[it][nt][2] - mx);
      float p3 = __expf(s[it][nt][3] - mx);
      l += (p0 + p1) + (p2 + p3);
      union { __hip_bfloat162 h2[2]; s16x4 v; } pu;
      pu.h2[0] = __float22bfloat162_rn(make_float2(p0, p1));
      pu.h2[1] = __float22bfloat162_rn(make_float2(p2, p3));
      pf[it][nt] = pu.v;
    }
  l += __shfl_xor(l, 16);
  l += __shfl_xor(l, 32);

  // ---- phase 4: O^T = V^T P^T (16 K=32 MFMAs; V frags coalesced from Vpv) ----
  f32x4 o0 = {}, o1 = {};
  const unsigned short* vp = Vpv + (size_t)b * 1024 * 128;   // [kg][32][4]
  #pragma unroll
  for (int it = 0; it < 4; it++)
    #pragma unroll
    for (int ntp = 0; ntp < 2; ntp++) {
      const int kg = ((gk0 + lkb + it * 64 + ntp * 32) >> 2) + g;
      const unsigned short* base0 = vp + ((size_t)kg * CK + c) * 4;
      union { s16x4 h[2]; bf16x8 v; } bu, a0u, a1u;
      bu.h[0]  = pf[it][ntp * 2];
      bu.h[1]  = pf[it][ntp * 2 + 1];
      a0u.h[0] = *(const s16x4*)(base0);            // keys kg*4..+3,  d=c
      a0u.h[1] = *(const s16x4*)(base0 + 512);      // +16 keys (4 kg blocks)
      a1u.h[0] = *(const s16x4*)(base0 + 64);       // d=16+c
      a1u.h[1] = *(const s16x4*)(base0 + 512 + 64);
      o0 = mfma16(a0u.v, bu.v, o0);                 // row=d(g*4+r), col=token(c)
      o1 = mfma16(a1u.v, bu.v, o1);
    }

  // ---- in-LDS merge of the 2 key-halves per token-half ----
  #pragma unroll
  for (int r = 0; r < 4; r++) {
    om[w][g * 4 + r][c]      = o0[r];
    om[w][16 + g * 4 + r][c] = o1[r];
  }
  if (lane < 16) { ml[w][0][lane] = mx; ml[w][1][lane] = l; }
  __syncthreads();
  {
    const int h = t >> 7, tok = (t >> 3) & 15, c0 = (t & 7) * 4;
    const int wA = h, wB = h + 2;
    float mA = ml[wA][0][tok], mB = ml[wB][0][tok];
    float mM = fmaxf(mA, mB);
    float fA = __expf(mA - mM), fB = __expf(mB - mM);
    float v[4];
    #pragma unroll
    for (int i = 0; i < 4; i++)
      v[i] = fA * om[wA][c0 + i][tok] + fB * om[wB][c0 + i][tok];
    float4 out = { v[0], v[1], v[2], v[3] };
    *(float4*)(partO + (size_t)blk * 1024 + (h * 16 + tok) * 32 + c0) = out;
    if (t < 32) {
      const int h2 = t >> 4, tk2 = t & 15;
      float mA2 = ml[h2][0][tk2], mB2 = ml[h2 + 2][0][tk2];
      float mT = fmaxf(mA2, mB2);
      float lsum = __expf(mA2 - mT) * ml[h2][1][tk2] +
                   __expf(mB2 - mT) * ml[h2 + 2][1][tk2];
      partML[(size_t)blk * 64 + h2 * 16 + tk2]      = mT;
      partML[(size_t)blk * 64 + 32 + h2 * 16 + tk2] = lsum;
    }
  }
}

// ---------------------------------------------------------------------------
// Merge 8 ksplit block-partials -> ON[b][tok][32] bf16 normalized.
// grid 256 x 256; thread = (b, qg, tok32, 4-chan group of 8).
// ---------------------------------------------------------------------------
__global__ __launch_bounds__(256) void merge_kernel(
    const float* __restrict__ partO, const float* __restrict__ partML,
    unsigned short* __restrict__ ON)
{
  const int gt = blockIdx.x * 256 + threadIdx.x;   // 65536 total
  const int ch4 = gt & 7, tok = (gt >> 3) & 31;
  const int qg = (gt >> 8) & 127, b = gt >> 15;
  const int blkbase = ((b << 7) + qg) << 3;
  float mv[8], lv[8], mM = -1e30f;
  #pragma unroll
  for (int k = 0; k < 8; k++) {
    mv[k] = partML[(size_t)(blkbase + k) * 64 + tok];
    lv[k] = partML[(size_t)(blkbase + k) * 64 + 32 + tok];
    mM = fmaxf(mM, mv[k]);
  }
  float lsum = 0.f, f[8];
  #pragma unroll
  for (int k = 0; k < 8; k++) {
    f[k] = __expf(mv[k] - mM);
    lsum = fmaf(f[k], lv[k], lsum);
  }
  const float inv = 1.0f / lsum;
  float acc[4] = {};
  #pragma unroll
  for (int k = 0; k < 8; k++) {
    float4 v = *(const float4*)(partO + (size_t)(blkbase + k) * 1024 + tok * 32 + ch4 * 4);
    acc[0] = fmaf(f[k], v.x, acc[0]); acc[1] = fmaf(f[k], v.y, acc[1]);
    acc[2] = fmaf(f[k], v.z, acc[2]); acc[3] = fmaf(f[k], v.w, acc[3]);
  }
  ushort4 u = { f2bf(acc[0] * inv), f2bf(acc[1] * inv),
                f2bf(acc[2] * inv), f2bf(acc[3] * inv) };
  *(ushort4*)(ON + ((size_t)(b * N_TOK + qg * 32 + tok)) * CK + ch4 * 4) = u;
}

// ---------------------------------------------------------------------------
// Output projection + residual: Y[b][o][t] = ON . W2^T + c2 + X.
// Grid 128 (b x 4 og x 16 tt) x 256 thr (4 waves of 16 o-rows).
// ---------------------------------------------------------------------------
__global__ __launch_bounds__(256) void oproj_kernel(
    const unsigned short* __restrict__ ON, const unsigned short* __restrict__ W2bf,
    const float* __restrict__ c2, const float* __restrict__ X,
    float* __restrict__ Y)
{
  const int blk = blockIdx.x;
  const int b  = blk >> 6;
  const int og = (blk >> 4) & 3;
  const int tt = blk & 15;
  const int t = threadIdx.x, w = t >> 6;
  const int lane = t & 63, c = lane & 15, g = lane >> 4;
  const int m0 = og * 64 + w * 16;
  const int t0 = tt * 256;
  bf16x8 aW = *(const bf16x8*)(W2bf + (size_t)(m0 + c) * CK + g * 8);
  f32x4 acc[16] = {};
  #pragma unroll
  for (int nt = 0; nt < 16; nt++) {
    bf16x8 bB = *(const bf16x8*)(ON + ((size_t)(b * N_TOK + t0 + nt * 16 + c)) * CK + g * 8);
    acc[nt] = mfma16(aW, bB, acc[nt]);
  }
  float cc2[4];
  #pragma unroll
  for (int r = 0; r < 4; r++) cc2[r] = c2[m0 + g * 4 + r];
  #pragma unroll
  for (int nt = 0; nt < 16; nt++)
    #pragma unroll
    for (int r = 0; r < 4; r++) {
      size_t idx = ((size_t)(b * CQ + m0 + g * 4 + r)) * N_TOK + t0 + nt * 16 + c;
      Y[idx] = acc[nt][r] + cc2[r] + X[idx];
    }
}

// ---------------------------------------------------------------------------
extern "C" void kernel_launch(void* const* d_in, const int* in_sizes, int n_in,
                              void* d_out, int out_size, void* d_ws, size_t ws_size,
                              hipStream_t stream) {
  const float* F  = (const float*)d_in[0];   // [2,256,4096]
  const float* Fk = (const float*)d_in[1];   // [2,32,4096]
  const float* Wq = (const float*)d_in[2];
  const float* bq = (const float*)d_in[3];
  const float* Wk = (const float*)d_in[4];
  // bk (d_in[5]) is provably softmax-invariant -> dropped
  const float* Wv = (const float*)d_in[6];
  const float* bv = (const float*)d_in[7];
  const float* Wo = (const float*)d_in[8];
  const float* bo = (const float*)d_in[9];
  float* Y = (float*)d_out;
  char* ws = (char*)d_ws;
  unsigned short* XkT   = (unsigned short*)(ws);                 // 512 KB [2,4096,32]
  unsigned short* Vpv   = (unsigned short*)(ws + (512u << 10));  // 512 KB [2,1024,32,4]
  unsigned short* ON    = (unsigned short*)(ws + (1024u << 10)); // 512 KB [2,4096,32]
  unsigned short* QN    = (unsigned short*)(ws + (1536u << 10)); // 512 KB [2,4096,32]
  unsigned short* Aqkt  = (unsigned short*)(ws + (2048u << 10)); // 16 KB  [32,256]
  unsigned short* W2bf  = (unsigned short*)(ws + (2080u << 10)); // 16 KB  [256,32]
  float*          bqk   = (float*)(ws + (2112u << 10));          // 128 B
  float*          c2    = (float*)(ws + (2116u << 10));          // 1 KB
  float*          partO = (float*)(ws + (4096u << 10));          // 8 MB  [2048][1024]
  float*          partML= (float*)(ws + (12288u << 10));         // 512 KB [2048][64]

  prep_kernel <<<128,  256, 0, stream>>>(Wq, bq, Wk, Wv, bv, Wo, bo, Fk,
                                         Aqkt, bqk, W2bf, c2, Vpv, XkT);
  qproj_kernel<<<256,  128, 0, stream>>>(F, Aqkt, bqk, QN);
  flash_kernel<<<2048, 256, 0, stream>>>(QN, XkT, Vpv, partO, partML);
  merge_kernel<<<256,  256, 0, stream>>>(partO, partML, ON);
  oproj_kernel<<<128,  256, 0, stream>>>(ON, W2bf, c2, F, Y);
}

// Round 10
// 149.480 us; speedup vs baseline: 1.1922x; 1.0185x over previous
//
#include <hip/hip_runtime.h>
#include <hip/hip_bf16.h>
#include <cstdint>
#include <cstddef>

#define N_TOK 4096
#define CQ    256
#define CK    32

typedef __attribute__((ext_vector_type(4))) float  f32x4;
typedef __attribute__((ext_vector_type(8))) __bf16 bf16x8;
typedef __attribute__((ext_vector_type(4))) short  s16x4;

__device__ __forceinline__ unsigned short f2bf(float f) {
  union { float f; unsigned u; } x; x.f = f;
  unsigned r = x.u + 0x7FFFu + ((x.u >> 16) & 1u);   // RNE
  return (unsigned short)(r >> 16);
}

__device__ __forceinline__ f32x4 mfma16(bf16x8 a, bf16x8 b, f32x4 c) {
  return __builtin_amdgcn_mfma_f32_16x16x32_bf16(a, b, c, 0, 0, 0);
}

// ---------------------------------------------------------------------------
// Prep: weight folds + xk bf16 prep. Grid 128 x 256.
//  blk 64..127: XkT[b][tok][ch] (QK A-frags, LDS-staged by flash) and
//               Vpv[b][key/4][d=32][4] -- PV A-fragment tiling (coalesced).
// ---------------------------------------------------------------------------
__global__ __launch_bounds__(256) void prep_kernel(
    const float* __restrict__ Wq, const float* __restrict__ bq,
    const float* __restrict__ Wk, const float* __restrict__ Wv,
    const float* __restrict__ bv, const float* __restrict__ Wo,
    const float* __restrict__ bo, const float* __restrict__ Fk,
    unsigned short* __restrict__ Aqkt, float* __restrict__ bqk,
    unsigned short* __restrict__ W2bf, float* __restrict__ c2,
    unsigned short* __restrict__ Vpv, unsigned short* __restrict__ XkT)
{
  __shared__ float red[256];
  __shared__ unsigned short trs[128][33];
  const int blk = blockIdx.x, t = threadIdx.x;
  if (blk < 32) {
    const int j = blk;
    float acc = 0.f;
    #pragma unroll 8
    for (int i = 0; i < CQ; i++)
      acc = fmaf(Wq[(size_t)i * CQ + t], Wk[(size_t)i * CK + j], acc);
    Aqkt[(size_t)j * CQ + t] = f2bf(0.125f * acc);
    red[t] = bq[t] * Wk[(size_t)t * CK + j];
    __syncthreads();
    for (int s = 128; s > 0; s >>= 1) {
      if (t < s) red[t] += red[t + s];
      __syncthreads();
    }
    if (t == 0) bqk[j] = 0.125f * red[0];
  } else if (blk < 64) {
    const int j = blk - 32;
    float acc = 0.f, acc2 = 0.f;
    #pragma unroll 8
    for (int i = 0; i < CQ; i++) {
      float wo = Wo[(size_t)t * CQ + i];
      acc  = fmaf(wo, Wv[(size_t)i * CK + j], acc);
      acc2 = fmaf(wo, bv[i], acc2);
    }
    W2bf[(size_t)t * CK + j] = f2bf(acc);
    if (j == 0) c2[t] = bo[t] + acc2;
  } else {
    const int blk2 = blk - 64;
    const int b = blk2 >> 5;
    const int t0 = (blk2 & 31) << 7;
    #pragma unroll
    for (int i = 0; i < 4; i++) {
      int flat = (i * 256 + t) << 2;            // over [32 ch][128 tok]
      int r = flat >> 7, c4 = flat & 127;
      float4 v = *(const float4*)(Fk + ((size_t)(b * CK + r)) * N_TOK + t0 + c4);
      ushort4 u = { f2bf(v.x), f2bf(v.y), f2bf(v.z), f2bf(v.w) };
      trs[c4][r] = u.x; trs[c4+1][r] = u.y; trs[c4+2][r] = u.z; trs[c4+3][r] = u.w;
    }
    __syncthreads();
    {   // XkT: token-major (coalesced 32B/thread)
      const int token = t >> 1, half = t & 1;
      unsigned short tmp[16] __attribute__((aligned(16)));
      #pragma unroll
      for (int k = 0; k < 16; k++) tmp[k] = trs[token][half * 16 + k];
      unsigned short* dst = XkT + ((size_t)(b * N_TOK + t0 + token)) * CK + half * 16;
      ((uint4*)dst)[0] = ((const uint4*)tmp)[0];
      ((uint4*)dst)[1] = ((const uint4*)tmp)[1];
    }
    {   // Vpv[kg][d][dk]: PV A-frag tiling (coalesced 32B/thread)
      const int kgl = t >> 3, d0 = (t & 7) * 4;
      unsigned short tmp[16] __attribute__((aligned(16)));
      #pragma unroll
      for (int di = 0; di < 4; di++)
        #pragma unroll
        for (int dk = 0; dk < 4; dk++)
          tmp[di * 4 + dk] = trs[kgl * 4 + dk][d0 + di];
      unsigned short* dst = Vpv +
          (((size_t)b * 1024 + (t0 >> 2) + kgl) * CK + d0) * 4;
      ((uint4*)dst)[0] = ((const uint4*)tmp)[0];
      ((uint4*)dst)[1] = ((const uint4*)tmp)[1];
    }
  }
}

// ---------------------------------------------------------------------------
// Q'' projection: QN[b][tok][32] = bf16( xq . Aqk + bqk )  (SCALE folded)
// grid 256 (b x 128 token-tiles of 32) x 128 thr (2 waves of 16 tokens).
// ---------------------------------------------------------------------------
__global__ __launch_bounds__(128) void qproj_kernel(
    const float* __restrict__ X, const unsigned short* __restrict__ Aqkt,
    const float* __restrict__ bqk, unsigned short* __restrict__ QN)
{
  __shared__ unsigned short bs[32][40];
  const int b = blockIdx.x >> 7;
  const int t0 = (blockIdx.x & 127) << 5;
  const int t = threadIdx.x, w = t >> 6;
  const int lane = t & 63, c = lane & 15, g = lane >> 4;
  f32x4 acc[2] = {};
  for (int k0 = 0; k0 < CQ; k0 += 32) {
    #pragma unroll
    for (int i = 0; i < 2; i++) {            // stage X [32c][32tok] -> bs[tok][c]
      int flat = (i * 128 + t) << 2;
      int cc = flat >> 5, tk = flat & 31;
      float4 v = *(const float4*)(X + ((size_t)(b * CQ + k0 + cc)) * N_TOK + t0 + tk);
      bs[tk  ][cc] = f2bf(v.x); bs[tk+1][cc] = f2bf(v.y);
      bs[tk+2][cc] = f2bf(v.z); bs[tk+3][cc] = f2bf(v.w);
    }
    __syncthreads();
    bf16x8 a = *(const bf16x8*)&bs[w * 16 + c][g * 8];
    #pragma unroll
    for (int nt = 0; nt < 2; nt++) {
      bf16x8 bB = *(const bf16x8*)(Aqkt + (size_t)(nt * 16 + c) * CQ + k0 + g * 8);
      acc[nt] = mfma16(a, bB, acc[nt]);
    }
    __syncthreads();
  }
  #pragma unroll
  for (int nt = 0; nt < 2; nt++) {
    float bj = bqk[nt * 16 + c];
    #pragma unroll
    for (int r = 0; r < 4; r++)
      QN[((size_t)(b * N_TOK + t0 + w * 16 + g * 4 + r)) * CK + nt * 16 + c] =
          f2bf(acc[nt][r] + bj);
  }
}

// ---------------------------------------------------------------------------
// Flash. Grid 2048 = (b, qg(64 of 64 tok), ksp(16 of 256 keys)) x 256 thr.
// All 4 waves share ONE 20KB staged K slice; wave = 16 tokens x all 256 keys
// -> no cross-wave merge, ONE barrier per block, partials written straight
// from registers. __launch_bounds__(256,5): 20 waves/CU.
// r9 postmortem: staging decomposed key rows as 2x16B (row=flat>>1) -- but a
// row is 64B=4 units. OOB LDS writes + half-unwritten rows -> NaN. Fixed:
// row=flat>>2, part=flat&3 (the r7/r8-verified decomposition).
// ---------------------------------------------------------------------------
__global__ __launch_bounds__(256, 5) void flash_kernel(
    const unsigned short* __restrict__ QN, const unsigned short* __restrict__ XkT,
    const unsigned short* __restrict__ Vpv, float* __restrict__ partO,
    float* __restrict__ partML)
{
  __shared__ unsigned short ks[256 * 40] __attribute__((aligned(16)));  // 20 KB
  const int blk = blockIdx.x;
  const int b   = blk >> 10;
  const int qg  = (blk >> 4) & 63;
  const int ksp = blk & 15;
  const int t = threadIdx.x, w = t >> 6;
  const int lane = t & 63, c = lane & 15, g = lane >> 4;
  const int t0 = qg * 64 + w * 16;
  const int gk0 = ksp * 256;

  // ---- cooperative stage: XkT[b][gk0 .. gk0+256)[32] -> ks (stride 40 sh) ----
  {
    const unsigned short* src = XkT + ((size_t)(b * N_TOK + gk0)) * CK;
    #pragma unroll
    for (int r = 0; r < 4; r++) {
      int flat = r * 256 + t;                  // 1024 x 16B units over 16KB
      int row = flat >> 2, part = flat & 3;    // key row = 64B = 4 units
      *(uint4*)(ks + row * 40 + part * 8) = *(const uint4*)(src + (size_t)flat * 8);
    }
  }
  const bf16x8 qf = *(const bf16x8*)(QN + ((size_t)(b * N_TOK + t0 + c)) * CK + g * 8);
  __syncthreads();

  // ---- phase 1: S^T for 256 keys (16 independent MFMAs, frags from LDS) ----
  f32x4 s[4][4];
  #pragma unroll
  for (int it = 0; it < 4; it++)
    #pragma unroll
    for (int nt = 0; nt < 4; nt++) {
      bf16x8 ak = *(const bf16x8*)&ks[(it * 64 + nt * 16 + c) * 40 + g * 8];
      f32x4 z = {};
      s[it][nt] = mfma16(ak, qf, z);           // row=key(g*4+r), col=token(c)
    }

  // ---- phase 2: per-token max ----
  float mx = -1e30f;
  #pragma unroll
  for (int it = 0; it < 4; it++)
    #pragma unroll
    for (int nt = 0; nt < 4; nt++)
      mx = fmaxf(mx, fmaxf(fmaxf(s[it][nt][0], s[it][nt][1]),
                           fmaxf(s[it][nt][2], s[it][nt][3])));
  mx = fmaxf(mx, __shfl_xor(mx, 16));
  mx = fmaxf(mx, __shfl_xor(mx, 32));

  // ---- phase 3: exp, sum, pack P^T (packed cvt, register-resident) ----
  float l = 0.f;
  s16x4 pf[4][4];
  #pragma unroll
  for (int it = 0; it < 4; it++)
    #pragma unroll
    for (int nt = 0; nt < 4; nt++) {
      float p0 = __expf(s[it][nt][0] - mx);
      float p1 = __expf(s[it][nt][1] - mx);
      float p2 = __expf(s[it][nt][2] - mx);
      float p3 = __expf(s[it][nt][3] - mx);
      l += (p0 + p1) + (p2 + p3);
      union { __hip_bfloat162 h2[2]; s16x4 v; } pu;
      pu.h2[0] = __float22bfloat162_rn(make_float2(p0, p1));
      pu.h2[1] = __float22bfloat162_rn(make_float2(p2, p3));
      pf[it][nt] = pu.v;
    }
  l += __shfl_xor(l, 16);
  l += __shfl_xor(l, 32);

  // ---- phase 4: O^T = V^T P^T (16 K=32 MFMAs; V frags coalesced from Vpv) ----
  f32x4 o0 = {}, o1 = {};
  const unsigned short* vp = Vpv + (size_t)b * 1024 * 128;   // [kg][32][4]
  #pragma unroll
  for (int it = 0; it < 4; it++)
    #pragma unroll
    for (int ntp = 0; ntp < 2; ntp++) {
      const int kg = ((gk0 + it * 64 + ntp * 32) >> 2) + g;
      const unsigned short* base0 = vp + ((size_t)kg * CK + c) * 4;
      union { s16x4 h[2]; bf16x8 v; } bu, a0u, a1u;
      bu.h[0]  = pf[it][ntp * 2];
      bu.h[1]  = pf[it][ntp * 2 + 1];
      a0u.h[0] = *(const s16x4*)(base0);            // keys kg*4..+3,  d=c
      a0u.h[1] = *(const s16x4*)(base0 + 512);      // +16 keys (4 kg blocks)
      a1u.h[0] = *(const s16x4*)(base0 + 64);       // d=16+c
      a1u.h[1] = *(const s16x4*)(base0 + 512 + 64);
      o0 = mfma16(a0u.v, bu.v, o0);                 // row=d(g*4+r), col=token(c)
      o1 = mfma16(a1u.v, bu.v, o1);
    }

  // ---- epilogue: per-wave partials straight from registers ----
  float* po = partO + (size_t)blk * 2048 + (w * 16 + c) * 32;
  *(f32x4*)(po + g * 4)      = o0;
  *(f32x4*)(po + 16 + g * 4) = o1;
  if (lane < 16) {
    partML[(size_t)blk * 128 + w * 16 + lane]      = mx;
    partML[(size_t)blk * 128 + 64 + w * 16 + lane] = l;
  }
}

// ---------------------------------------------------------------------------
// Merge 16 ksplit partials -> ON[b][tok][32] bf16 normalized.
// grid 256 x 256; thread = (b, tok, 4-chan group of 8).
// ---------------------------------------------------------------------------
__global__ __launch_bounds__(256) void merge_kernel(
    const float* __restrict__ partO, const float* __restrict__ partML,
    unsigned short* __restrict__ ON)
{
  const int gt = blockIdx.x * 256 + threadIdx.x;   // 65536 total
  const int ch4 = gt & 7;
  const int q  = (gt >> 3) & 4095;
  const int b  = gt >> 15;
  const int qg = q >> 6, tl = q & 63;
  const int blkbase = b * 1024 + qg * 16;
  float mv[16], lv[16], mM = -1e30f;
  #pragma unroll
  for (int k = 0; k < 16; k++) {
    mv[k] = partML[(size_t)(blkbase + k) * 128 + tl];
    lv[k] = partML[(size_t)(blkbase + k) * 128 + 64 + tl];
    mM = fmaxf(mM, mv[k]);
  }
  float lsum = 0.f, f[16];
  #pragma unroll
  for (int k = 0; k < 16; k++) {
    f[k] = __expf(mv[k] - mM);
    lsum = fmaf(f[k], lv[k], lsum);
  }
  const float inv = 1.0f / lsum;
  float acc[4] = {};
  #pragma unroll
  for (int k = 0; k < 16; k++) {
    float4 v = *(const float4*)(partO + (size_t)(blkbase + k) * 2048 + tl * 32 + ch4 * 4);
    acc[0] = fmaf(f[k], v.x, acc[0]); acc[1] = fmaf(f[k], v.y, acc[1]);
    acc[2] = fmaf(f[k], v.z, acc[2]); acc[3] = fmaf(f[k], v.w, acc[3]);
  }
  ushort4 u = { f2bf(acc[0] * inv), f2bf(acc[1] * inv),
                f2bf(acc[2] * inv), f2bf(acc[3] * inv) };
  *(ushort4*)(ON + ((size_t)(b * N_TOK + q)) * CK + ch4 * 4) = u;
}

// ---------------------------------------------------------------------------
// Output projection + residual: Y[b][o][t] = ON . W2^T + c2 + X.
// Grid 128 (b x 4 og x 16 tt) x 256 thr (4 waves of 16 o-rows).
// ---------------------------------------------------------------------------
__global__ __launch_bounds__(256) void oproj_kernel(
    const unsigned short* __restrict__ ON, const unsigned short* __restrict__ W2bf,
    const float* __restrict__ c2, const float* __restrict__ X,
    float* __restrict__ Y)
{
  const int blk = blockIdx.x;
  const int b  = blk >> 6;
  const int og = (blk >> 4) & 3;
  const int tt = blk & 15;
  const int t = threadIdx.x, w = t >> 6;
  const int lane = t & 63, c = lane & 15, g = lane >> 4;
  const int m0 = og * 64 + w * 16;
  const int t0 = tt * 256;
  bf16x8 aW = *(const bf16x8*)(W2bf + (size_t)(m0 + c) * CK + g * 8);
  f32x4 acc[16] = {};
  #pragma unroll
  for (int nt = 0; nt < 16; nt++) {
    bf16x8 bB = *(const bf16x8*)(ON + ((size_t)(b * N_TOK + t0 + nt * 16 + c)) * CK + g * 8);
    acc[nt] = mfma16(aW, bB, acc[nt]);
  }
  float cc2[4];
  #pragma unroll
  for (int r = 0; r < 4; r++) cc2[r] = c2[m0 + g * 4 + r];
  #pragma unroll
  for (int nt = 0; nt < 16; nt++)
    #pragma unroll
    for (int r = 0; r < 4; r++) {
      size_t idx = ((size_t)(b * CQ + m0 + g * 4 + r)) * N_TOK + t0 + nt * 16 + c;
      Y[idx] = acc[nt][r] + cc2[r] + X[idx];
    }
}

// ---------------------------------------------------------------------------
extern "C" void kernel_launch(void* const* d_in, const int* in_sizes, int n_in,
                              void* d_out, int out_size, void* d_ws, size_t ws_size,
                              hipStream_t stream) {
  const float* F  = (const float*)d_in[0];   // [2,256,4096]
  const float* Fk = (const float*)d_in[1];   // [2,32,4096]
  const float* Wq = (const float*)d_in[2];
  const float* bq = (const float*)d_in[3];
  const float* Wk = (const float*)d_in[4];
  // bk (d_in[5]) is provably softmax-invariant -> dropped
  const float* Wv = (const float*)d_in[6];
  const float* bv = (const float*)d_in[7];
  const float* Wo = (const float*)d_in[8];
  const float* bo = (const float*)d_in[9];
  float* Y = (float*)d_out;
  char* ws = (char*)d_ws;
  unsigned short* XkT   = (unsigned short*)(ws);                 // 512 KB [2,4096,32]
  unsigned short* Vpv   = (unsigned short*)(ws + (512u << 10));  // 512 KB [2,1024,32,4]
  unsigned short* ON    = (unsigned short*)(ws + (1024u << 10)); // 512 KB [2,4096,32]
  unsigned short* QN    = (unsigned short*)(ws + (1536u << 10)); // 512 KB [2,4096,32]
  unsigned short* Aqkt  = (unsigned short*)(ws + (2048u << 10)); // 16 KB  [32,256]
  unsigned short* W2bf  = (unsigned short*)(ws + (2080u << 10)); // 16 KB  [256,32]
  float*          bqk   = (float*)(ws + (2112u << 10));          // 128 B
  float*          c2    = (float*)(ws + (2116u << 10));          // 1 KB
  float*          partO = (float*)(ws + (4096u << 10));          // 16 MB [2048][2048]
  float*          partML= (float*)(ws + (20480u << 10));         // 1 MB  [2048][128]

  prep_kernel <<<128,  256, 0, stream>>>(Wq, bq, Wk, Wv, bv, Wo, bo, Fk,
                                         Aqkt, bqk, W2bf, c2, Vpv, XkT);
  qproj_kernel<<<256,  128, 0, stream>>>(F, Aqkt, bqk, QN);
  flash_kernel<<<2048, 256, 0, stream>>>(QN, XkT, Vpv, partO, partML);
  merge_kernel<<<256,  256, 0, stream>>>(partO, partML, ON);
  oproj_kernel<<<128,  256, 0, stream>>>(ON, W2bf, c2, F, Y);
}

// Round 11
// 132.068 us; speedup vs baseline: 1.3493x; 1.1318x over previous
//
#include <hip/hip_runtime.h>
#include <hip/hip_bf16.h>
#include <cstdint>
#include <cstddef>

#define N_TOK 4096
#define CQ    256
#define CK    32

typedef __attribute__((ext_vector_type(4))) float  f32x4;
typedef __attribute__((ext_vector_type(8))) __bf16 bf16x8;
typedef __attribute__((ext_vector_type(4))) short  s16x4;

__device__ __forceinline__ unsigned short f2bf(float f) {
  union { float f; unsigned u; } x; x.f = f;
  unsigned r = x.u + 0x7FFFu + ((x.u >> 16) & 1u);   // RNE
  return (unsigned short)(r >> 16);
}

__device__ __forceinline__ f32x4 mfma16(bf16x8 a, bf16x8 b, f32x4 c) {
  return __builtin_amdgcn_mfma_f32_16x16x32_bf16(a, b, c, 0, 0, 0);
}

// slot permutation (r8-verified): pos = g*8+j  <->  key_local in 32-key chunk
__device__ __forceinline__ int pos2key(int pos) {
  return ((pos >> 3) << 2) + (pos & 3) + (((pos >> 2) & 1) << 4);
}

// ---------------------------------------------------------------------------
// Prep: weight folds + xk bf16 prep. Grid 128 x 256.
//  blk 64..127: XkT[b][tok][ch] (QK A-frags, LDS-staged by flash) and
//  Vpv[b][chunk32][d=32][pos=32] -- PV A-frag, slot-permutation-major, so
//  flash's V fragment = ONE coalesced 16B load.
// ---------------------------------------------------------------------------
__global__ __launch_bounds__(256) void prep_kernel(
    const float* __restrict__ Wq, const float* __restrict__ bq,
    const float* __restrict__ Wk, const float* __restrict__ Wv,
    const float* __restrict__ bv, const float* __restrict__ Wo,
    const float* __restrict__ bo, const float* __restrict__ Fk,
    unsigned short* __restrict__ Aqkt, float* __restrict__ bqk,
    unsigned short* __restrict__ W2bf, float* __restrict__ c2,
    unsigned short* __restrict__ Vpv, unsigned short* __restrict__ XkT)
{
  __shared__ float red[256];
  __shared__ unsigned short trs[128][33];
  const int blk = blockIdx.x, t = threadIdx.x;
  if (blk < 32) {
    const int j = blk;
    float acc = 0.f;
    #pragma unroll 8
    for (int i = 0; i < CQ; i++)
      acc = fmaf(Wq[(size_t)i * CQ + t], Wk[(size_t)i * CK + j], acc);
    Aqkt[(size_t)j * CQ + t] = f2bf(0.125f * acc);
    red[t] = bq[t] * Wk[(size_t)t * CK + j];
    __syncthreads();
    for (int s = 128; s > 0; s >>= 1) {
      if (t < s) red[t] += red[t + s];
      __syncthreads();
    }
    if (t == 0) bqk[j] = 0.125f * red[0];
  } else if (blk < 64) {
    const int j = blk - 32;
    float acc = 0.f, acc2 = 0.f;
    #pragma unroll 8
    for (int i = 0; i < CQ; i++) {
      float wo = Wo[(size_t)t * CQ + i];
      acc  = fmaf(wo, Wv[(size_t)i * CK + j], acc);
      acc2 = fmaf(wo, bv[i], acc2);
    }
    W2bf[(size_t)t * CK + j] = f2bf(acc);
    if (j == 0) c2[t] = bo[t] + acc2;
  } else {
    const int blk2 = blk - 64;
    const int b = blk2 >> 5;
    const int t0 = (blk2 & 31) << 7;
    #pragma unroll
    for (int i = 0; i < 4; i++) {
      int flat = (i * 256 + t) << 2;            // over [32 ch][128 tok]
      int r = flat >> 7, c4 = flat & 127;
      float4 v = *(const float4*)(Fk + ((size_t)(b * CK + r)) * N_TOK + t0 + c4);
      ushort4 u = { f2bf(v.x), f2bf(v.y), f2bf(v.z), f2bf(v.w) };
      trs[c4][r] = u.x; trs[c4+1][r] = u.y; trs[c4+2][r] = u.z; trs[c4+3][r] = u.w;
    }
    __syncthreads();
    {   // XkT: token-major (coalesced 32B/thread)
      const int token = t >> 1, half = t & 1;
      unsigned short tmp[16] __attribute__((aligned(16)));
      #pragma unroll
      for (int k = 0; k < 16; k++) tmp[k] = trs[token][half * 16 + k];
      unsigned short* dst = XkT + ((size_t)(b * N_TOK + t0 + token)) * CK + half * 16;
      ((uint4*)dst)[0] = ((const uint4*)tmp)[0];
      ((uint4*)dst)[1] = ((const uint4*)tmp)[1];
    }
    {   // Vpv[chunk32][d][pos]: thread = (chunk-local(4), d(32), pos-half(2))
      const int ch32l = t >> 6, d = (t & 63) >> 1, ph = t & 1;
      unsigned short tmp[16] __attribute__((aligned(16)));
      #pragma unroll
      for (int i = 0; i < 16; i++) {
        int pos = ph * 16 + i;
        tmp[i] = trs[ch32l * 32 + pos2key(pos)][d];
      }
      unsigned short* dst = Vpv +
          (((size_t)(b * 128 + (t0 >> 5) + ch32l)) * 32 + d) * 32 + ph * 16;
      ((uint4*)dst)[0] = ((const uint4*)tmp)[0];
      ((uint4*)dst)[1] = ((const uint4*)tmp)[1];
    }
  }
}

// ---------------------------------------------------------------------------
// Q'' projection: QN[b][tok][32] = bf16( xq . Aqk + bqk )  (SCALE folded)
// grid 256 (b x 128 token-tiles of 32) x 128 thr (2 waves of 16 tokens).
// ---------------------------------------------------------------------------
__global__ __launch_bounds__(128) void qproj_kernel(
    const float* __restrict__ X, const unsigned short* __restrict__ Aqkt,
    const float* __restrict__ bqk, unsigned short* __restrict__ QN)
{
  __shared__ unsigned short bs[32][40];
  const int b = blockIdx.x >> 7;
  const int t0 = (blockIdx.x & 127) << 5;
  const int t = threadIdx.x, w = t >> 6;
  const int lane = t & 63, c = lane & 15, g = lane >> 4;
  f32x4 acc[2] = {};
  for (int k0 = 0; k0 < CQ; k0 += 32) {
    #pragma unroll
    for (int i = 0; i < 2; i++) {            // stage X [32c][32tok] -> bs[tok][c]
      int flat = (i * 128 + t) << 2;
      int cc = flat >> 5, tk = flat & 31;
      float4 v = *(const float4*)(X + ((size_t)(b * CQ + k0 + cc)) * N_TOK + t0 + tk);
      bs[tk  ][cc] = f2bf(v.x); bs[tk+1][cc] = f2bf(v.y);
      bs[tk+2][cc] = f2bf(v.z); bs[tk+3][cc] = f2bf(v.w);
    }
    __syncthreads();
    bf16x8 a = *(const bf16x8*)&bs[w * 16 + c][g * 8];
    #pragma unroll
    for (int nt = 0; nt < 2; nt++) {
      bf16x8 bB = *(const bf16x8*)(Aqkt + (size_t)(nt * 16 + c) * CQ + k0 + g * 8);
      acc[nt] = mfma16(a, bB, acc[nt]);
    }
    __syncthreads();
  }
  #pragma unroll
  for (int nt = 0; nt < 2; nt++) {
    float bj = bqk[nt * 16 + c];
    #pragma unroll
    for (int r = 0; r < 4; r++)
      QN[((size_t)(b * N_TOK + t0 + w * 16 + g * 4 + r)) * CK + nt * 16 + c] =
          f2bf(acc[nt][r] + bj);
  }
}

// ---------------------------------------------------------------------------
// Flash. Grid 2048 = (b, qg(64 of 64 tok), ksp(16 of 256 keys)) x 256 thr.
// All 4 waves share ONE 20KB staged K slice; wave = 16 tokens x 256 keys,
// flat softmax, P^T register-resident, V A-frags = single 16B coalesced loads
// from the slot-permuted Vpv. One barrier; partials straight from registers.
// ---------------------------------------------------------------------------
__global__ __launch_bounds__(256, 5) void flash_kernel(
    const unsigned short* __restrict__ QN, const unsigned short* __restrict__ XkT,
    const unsigned short* __restrict__ Vpv, float* __restrict__ partO,
    float* __restrict__ partML)
{
  __shared__ unsigned short ks[256 * 40] __attribute__((aligned(16)));  // 20 KB
  const int blk = blockIdx.x;
  const int b   = blk >> 10;
  const int qg  = (blk >> 4) & 63;
  const int ksp = blk & 15;
  const int t = threadIdx.x, w = t >> 6;
  const int lane = t & 63, c = lane & 15, g = lane >> 4;
  const int t0 = qg * 64 + w * 16;
  const int gk0 = ksp * 256;

  // ---- cooperative stage: XkT[b][gk0 .. gk0+256)[32] -> ks (stride 40 sh) ----
  {
    const unsigned short* src = XkT + ((size_t)(b * N_TOK + gk0)) * CK;
    #pragma unroll
    for (int r = 0; r < 4; r++) {
      int flat = r * 256 + t;                  // 1024 x 16B units over 16KB
      int row = flat >> 2, part = flat & 3;    // key row = 64B = 4 units
      *(uint4*)(ks + row * 40 + part * 8) = *(const uint4*)(src + (size_t)flat * 8);
    }
  }
  const bf16x8 qf = *(const bf16x8*)(QN + ((size_t)(b * N_TOK + t0 + c)) * CK + g * 8);
  __syncthreads();

  // ---- phase 1: S^T for 256 keys (16 independent MFMAs, frags from LDS) ----
  f32x4 s[4][4];
  #pragma unroll
  for (int it = 0; it < 4; it++)
    #pragma unroll
    for (int nt = 0; nt < 4; nt++) {
      bf16x8 ak = *(const bf16x8*)&ks[(it * 64 + nt * 16 + c) * 40 + g * 8];
      f32x4 z = {};
      s[it][nt] = mfma16(ak, qf, z);           // row=key(g*4+r), col=token(c)
    }

  // ---- phase 2: per-token max ----
  float mx = -1e30f;
  #pragma unroll
  for (int it = 0; it < 4; it++)
    #pragma unroll
    for (int nt = 0; nt < 4; nt++)
      mx = fmaxf(mx, fmaxf(fmaxf(s[it][nt][0], s[it][nt][1]),
                           fmaxf(s[it][nt][2], s[it][nt][3])));
  mx = fmaxf(mx, __shfl_xor(mx, 16));
  mx = fmaxf(mx, __shfl_xor(mx, 32));

  // ---- phase 3: exp, sum, pack P^T (packed cvt, register-resident) ----
  float l = 0.f;
  s16x4 pf[4][4];
  #pragma unroll
  for (int it = 0; it < 4; it++)
    #pragma unroll
    for (int nt = 0; nt < 4; nt++) {
      float p0 = __expf(s[it][nt][0] - mx);
      float p1 = __expf(s[it][nt][1] - mx);
      float p2 = __expf(s[it][nt][2] - mx);
      float p3 = __expf(s[it][nt][3] - mx);
      l += (p0 + p1) + (p2 + p3);
      union { __hip_bfloat162 h2[2]; s16x4 v; } pu;
      pu.h2[0] = __float22bfloat162_rn(make_float2(p0, p1));
      pu.h2[1] = __float22bfloat162_rn(make_float2(p2, p3));
      pf[it][nt] = pu.v;
    }
  l += __shfl_xor(l, 16);
  l += __shfl_xor(l, 32);

  // ---- phase 4: O^T = V^T P^T (16 K=32 MFMAs; 16B coalesced V frags) ----
  f32x4 o0 = {}, o1 = {};
  const unsigned short* vp = Vpv + (size_t)b * 128 * 1024;   // [ch32][32d][32pos]
  #pragma unroll
  for (int it = 0; it < 4; it++)
    #pragma unroll
    for (int ntp = 0; ntp < 2; ntp++) {
      const int ch32 = (gk0 + it * 64 + ntp * 32) >> 5;
      const unsigned short* base = vp + (size_t)ch32 * 1024;
      union { s16x4 h[2]; bf16x8 v; } bu;
      bu.h[0] = pf[it][ntp * 2];
      bu.h[1] = pf[it][ntp * 2 + 1];
      bf16x8 a0 = *(const bf16x8*)(base + c * 32 + g * 8);          // d=c
      bf16x8 a1 = *(const bf16x8*)(base + (16 + c) * 32 + g * 8);   // d=16+c
      o0 = mfma16(a0, bu.v, o0);                // row=d(g*4+r), col=token(c)
      o1 = mfma16(a1, bu.v, o1);
    }

  // ---- epilogue: per-wave partials straight from registers ----
  float* po = partO + (size_t)blk * 2048 + (w * 16 + c) * 32;
  *(f32x4*)(po + g * 4)      = o0;
  *(f32x4*)(po + 16 + g * 4) = o1;
  if (lane < 16) {
    partML[(size_t)blk * 128 + w * 16 + lane]      = mx;
    partML[(size_t)blk * 128 + 64 + w * 16 + lane] = l;
  }
}

// ---------------------------------------------------------------------------
// Fused merge + output projection + residual.
// Grid 256 = (b, tt(128 of 32 tok)) x 256 thr (4 waves).
// Phase A: merge 16 ksplit partials for the 32 tokens -> LDS ON tile (bf16).
// Phase B: Y[b][o][t0..t0+32) = W2 @ ON^T + c2 + X  (wave = 64 out rows).
// ---------------------------------------------------------------------------
__global__ __launch_bounds__(256) void oproj_kernel(
    const float* __restrict__ partO, const float* __restrict__ partML,
    const unsigned short* __restrict__ W2bf, const float* __restrict__ c2,
    const float* __restrict__ X, float* __restrict__ Y)
{
  __shared__ unsigned short ons[32][40];
  const int blk = blockIdx.x;
  const int b = blk >> 7, tt = blk & 127;
  const int t = threadIdx.x, w = t >> 6;
  const int lane = t & 63, c = lane & 15, g = lane >> 4;
  const int t0 = tt * 32;

  // ---- phase A: thread = (tok32, ch4-group) ----
  {
    const int tl32 = t >> 3, ch4 = t & 7;
    const int q  = t0 + tl32;
    const int qg = q >> 6, tl = q & 63;
    const int blkbase = (b << 10) + qg * 16;
    float mv[16], lv[16], mM = -1e30f;
    #pragma unroll
    for (int k = 0; k < 16; k++) {
      mv[k] = partML[(size_t)(blkbase + k) * 128 + tl];
      lv[k] = partML[(size_t)(blkbase + k) * 128 + 64 + tl];
      mM = fmaxf(mM, mv[k]);
    }
    float lsum = 0.f, f[16];
    #pragma unroll
    for (int k = 0; k < 16; k++) {
      f[k] = __expf(mv[k] - mM);
      lsum = fmaf(f[k], lv[k], lsum);
    }
    const float inv = 1.0f / lsum;
    float acc[4] = {};
    #pragma unroll
    for (int k = 0; k < 16; k++) {
      float4 v = *(const float4*)(partO + (size_t)(blkbase + k) * 2048 + tl * 32 + ch4 * 4);
      acc[0] = fmaf(f[k], v.x, acc[0]); acc[1] = fmaf(f[k], v.y, acc[1]);
      acc[2] = fmaf(f[k], v.z, acc[2]); acc[3] = fmaf(f[k], v.w, acc[3]);
    }
    ons[tl32][ch4 * 4    ] = f2bf(acc[0] * inv);
    ons[tl32][ch4 * 4 + 1] = f2bf(acc[1] * inv);
    ons[tl32][ch4 * 4 + 2] = f2bf(acc[2] * inv);
    ons[tl32][ch4 * 4 + 3] = f2bf(acc[3] * inv);
  }
  __syncthreads();

  // ---- phase B: wave w owns out rows [w*64, w*64+64) ----
  const int m0 = w * 64;
  bf16x8 bB[2];
  #pragma unroll
  for (int nt = 0; nt < 2; nt++)
    bB[nt] = *(const bf16x8*)&ons[nt * 16 + c][g * 8];
  f32x4 acc[4][2] = {};
  #pragma unroll
  for (int mt = 0; mt < 4; mt++) {
    bf16x8 aW = *(const bf16x8*)(W2bf + (size_t)(m0 + mt * 16 + c) * CK + g * 8);
    acc[mt][0] = mfma16(aW, bB[0], acc[mt][0]);
    acc[mt][1] = mfma16(aW, bB[1], acc[mt][1]);
  }
  #pragma unroll
  for (int mt = 0; mt < 4; mt++)
    #pragma unroll
    for (int r = 0; r < 4; r++) {
      const int row = m0 + mt * 16 + g * 4 + r;
      const float cc = c2[row];
      #pragma unroll
      for (int nt = 0; nt < 2; nt++) {
        size_t idx = ((size_t)(b * CQ + row)) * N_TOK + t0 + nt * 16 + c;
        Y[idx] = acc[mt][nt][r] + cc + X[idx];
      }
    }
}

// ---------------------------------------------------------------------------
extern "C" void kernel_launch(void* const* d_in, const int* in_sizes, int n_in,
                              void* d_out, int out_size, void* d_ws, size_t ws_size,
                              hipStream_t stream) {
  const float* F  = (const float*)d_in[0];   // [2,256,4096]
  const float* Fk = (const float*)d_in[1];   // [2,32,4096]
  const float* Wq = (const float*)d_in[2];
  const float* bq = (const float*)d_in[3];
  const float* Wk = (const float*)d_in[4];
  // bk (d_in[5]) is provably softmax-invariant -> dropped
  const float* Wv = (const float*)d_in[6];
  const float* bv = (const float*)d_in[7];
  const float* Wo = (const float*)d_in[8];
  const float* bo = (const float*)d_in[9];
  float* Y = (float*)d_out;
  char* ws = (char*)d_ws;
  unsigned short* XkT   = (unsigned short*)(ws);                 // 512 KB [2,4096,32]
  unsigned short* Vpv   = (unsigned short*)(ws + (512u << 10));  // 512 KB [2,128,32,32]
  unsigned short* QN    = (unsigned short*)(ws + (1536u << 10)); // 512 KB [2,4096,32]
  unsigned short* Aqkt  = (unsigned short*)(ws + (2048u << 10)); // 16 KB  [32,256]
  unsigned short* W2bf  = (unsigned short*)(ws + (2080u << 10)); // 16 KB  [256,32]
  float*          bqk   = (float*)(ws + (2112u << 10));          // 128 B
  float*          c2    = (float*)(ws + (2116u << 10));          // 1 KB
  float*          partO = (float*)(ws + (4096u << 10));          // 16 MB [2048][2048]
  float*          partML= (float*)(ws + (20480u << 10));         // 1 MB  [2048][128]

  prep_kernel <<<128,  256, 0, stream>>>(Wq, bq, Wk, Wv, bv, Wo, bo, Fk,
                                         Aqkt, bqk, W2bf, c2, Vpv, XkT);
  qproj_kernel<<<256,  128, 0, stream>>>(F, Aqkt, bqk, QN);
  flash_kernel<<<2048, 256, 0, stream>>>(QN, XkT, Vpv, partO, partML);
  oproj_kernel<<<256,  256, 0, stream>>>(partO, partML, W2bf, c2, F, Y);
}

// Round 12
// 129.990 us; speedup vs baseline: 1.3709x; 1.0160x over previous
//
#include <hip/hip_runtime.h>
#include <hip/hip_bf16.h>
#include <cstdint>
#include <cstddef>

#define N_TOK 4096
#define CQ    256
#define CK    32

typedef __attribute__((ext_vector_type(4))) float  f32x4;
typedef __attribute__((ext_vector_type(8))) __bf16 bf16x8;
typedef __attribute__((ext_vector_type(4))) short  s16x4;

__device__ __forceinline__ unsigned short f2bf(float f) {
  union { float f; unsigned u; } x; x.f = f;
  unsigned r = x.u + 0x7FFFu + ((x.u >> 16) & 1u);   // RNE
  return (unsigned short)(r >> 16);
}

__device__ __forceinline__ f32x4 mfma16(bf16x8 a, bf16x8 b, f32x4 c) {
  return __builtin_amdgcn_mfma_f32_16x16x32_bf16(a, b, c, 0, 0, 0);
}

// slot permutation (r8-verified): pos = g*8+j  <->  key_local in 32-key chunk
__device__ __forceinline__ int pos2key(int pos) {
  return ((pos >> 3) << 2) + (pos & 3) + (((pos >> 2) & 1) << 4);
}

// ---------------------------------------------------------------------------
// Prep: weight folds + xk bf16 prep. Grid 128 x 256.
// (qproj cannot fuse here: it consumes Aqkt/bqk written by other blocks of
// the same dispatch -- intra-dispatch cross-block race.)
// ---------------------------------------------------------------------------
__global__ __launch_bounds__(256) void prep_kernel(
    const float* __restrict__ Wq, const float* __restrict__ bq,
    const float* __restrict__ Wk, const float* __restrict__ Wv,
    const float* __restrict__ bv, const float* __restrict__ Wo,
    const float* __restrict__ bo, const float* __restrict__ Fk,
    unsigned short* __restrict__ Aqkt, float* __restrict__ bqk,
    unsigned short* __restrict__ W2bf, float* __restrict__ c2,
    unsigned short* __restrict__ Vpv, unsigned short* __restrict__ XkT)
{
  __shared__ float red[256];
  __shared__ unsigned short trs[128][33];
  const int blk = blockIdx.x, t = threadIdx.x;
  if (blk < 32) {
    const int j = blk;
    float acc = 0.f;
    #pragma unroll 8
    for (int i = 0; i < CQ; i++)
      acc = fmaf(Wq[(size_t)i * CQ + t], Wk[(size_t)i * CK + j], acc);
    Aqkt[(size_t)j * CQ + t] = f2bf(0.125f * acc);
    red[t] = bq[t] * Wk[(size_t)t * CK + j];
    __syncthreads();
    for (int s = 128; s > 0; s >>= 1) {
      if (t < s) red[t] += red[t + s];
      __syncthreads();
    }
    if (t == 0) bqk[j] = 0.125f * red[0];
  } else if (blk < 64) {
    const int j = blk - 32;
    float acc = 0.f, acc2 = 0.f;
    #pragma unroll 8
    for (int i = 0; i < CQ; i++) {
      float wo = Wo[(size_t)t * CQ + i];
      acc  = fmaf(wo, Wv[(size_t)i * CK + j], acc);
      acc2 = fmaf(wo, bv[i], acc2);
    }
    W2bf[(size_t)t * CK + j] = f2bf(acc);
    if (j == 0) c2[t] = bo[t] + acc2;
  } else {
    const int blk2 = blk - 64;
    const int b = blk2 >> 5;
    const int t0 = (blk2 & 31) << 7;
    #pragma unroll
    for (int i = 0; i < 4; i++) {
      int flat = (i * 256 + t) << 2;            // over [32 ch][128 tok]
      int r = flat >> 7, c4 = flat & 127;
      float4 v = *(const float4*)(Fk + ((size_t)(b * CK + r)) * N_TOK + t0 + c4);
      ushort4 u = { f2bf(v.x), f2bf(v.y), f2bf(v.z), f2bf(v.w) };
      trs[c4][r] = u.x; trs[c4+1][r] = u.y; trs[c4+2][r] = u.z; trs[c4+3][r] = u.w;
    }
    __syncthreads();
    {   // XkT: token-major (coalesced 32B/thread)
      const int token = t >> 1, half = t & 1;
      unsigned short tmp[16] __attribute__((aligned(16)));
      #pragma unroll
      for (int k = 0; k < 16; k++) tmp[k] = trs[token][half * 16 + k];
      unsigned short* dst = XkT + ((size_t)(b * N_TOK + t0 + token)) * CK + half * 16;
      ((uint4*)dst)[0] = ((const uint4*)tmp)[0];
      ((uint4*)dst)[1] = ((const uint4*)tmp)[1];
    }
    {   // Vpv[chunk32][d][pos]: thread = (chunk-local(4), d(32), pos-half(2))
      const int ch32l = t >> 6, d = (t & 63) >> 1, ph = t & 1;
      unsigned short tmp[16] __attribute__((aligned(16)));
      #pragma unroll
      for (int i = 0; i < 16; i++) {
        int pos = ph * 16 + i;
        tmp[i] = trs[ch32l * 32 + pos2key(pos)][d];
      }
      unsigned short* dst = Vpv +
          (((size_t)(b * 128 + (t0 >> 5) + ch32l)) * 32 + d) * 32 + ph * 16;
      ((uint4*)dst)[0] = ((const uint4*)tmp)[0];
      ((uint4*)dst)[1] = ((const uint4*)tmp)[1];
    }
  }
}

// ---------------------------------------------------------------------------
// Q'' projection: QN[b][tok][32] = bf16( xq . Aqk + bqk )  (SCALE folded)
// grid 256 (b x 128 token-tiles of 32) x 128 thr (2 waves of 16 tokens).
// ---------------------------------------------------------------------------
__global__ __launch_bounds__(128) void qproj_kernel(
    const float* __restrict__ X, const unsigned short* __restrict__ Aqkt,
    const float* __restrict__ bqk, unsigned short* __restrict__ QN)
{
  __shared__ unsigned short bs[32][40];
  const int b = blockIdx.x >> 7;
  const int t0 = (blockIdx.x & 127) << 5;
  const int t = threadIdx.x, w = t >> 6;
  const int lane = t & 63, c = lane & 15, g = lane >> 4;
  f32x4 acc[2] = {};
  for (int k0 = 0; k0 < CQ; k0 += 32) {
    #pragma unroll
    for (int i = 0; i < 2; i++) {            // stage X [32c][32tok] -> bs[tok][c]
      int flat = (i * 128 + t) << 2;
      int cc = flat >> 5, tk = flat & 31;
      float4 v = *(const float4*)(X + ((size_t)(b * CQ + k0 + cc)) * N_TOK + t0 + tk);
      bs[tk  ][cc] = f2bf(v.x); bs[tk+1][cc] = f2bf(v.y);
      bs[tk+2][cc] = f2bf(v.z); bs[tk+3][cc] = f2bf(v.w);
    }
    __syncthreads();
    bf16x8 a = *(const bf16x8*)&bs[w * 16 + c][g * 8];
    #pragma unroll
    for (int nt = 0; nt < 2; nt++) {
      bf16x8 bB = *(const bf16x8*)(Aqkt + (size_t)(nt * 16 + c) * CQ + k0 + g * 8);
      acc[nt] = mfma16(a, bB, acc[nt]);
    }
    __syncthreads();
  }
  #pragma unroll
  for (int nt = 0; nt < 2; nt++) {
    float bj = bqk[nt * 16 + c];
    #pragma unroll
    for (int r = 0; r < 4; r++)
      QN[((size_t)(b * N_TOK + t0 + w * 16 + g * 4 + r)) * CK + nt * 16 + c] =
          f2bf(acc[nt][r] + bj);
  }
}

// ---------------------------------------------------------------------------
// Flash, two-pass. Grid 1024 = (b, qg(64 of 64 tok), ksp(8 of 512 keys)) x
// 256 thr. Block stages BOTH 256-key slices (40 KB LDS) behind ONE barrier;
// wave = 16 tokens, runs the verified flat-softmax pipeline twice (256 keys
// each) and merges the two (m,l,O) partials in registers (r7-verified math).
// 40 KB LDS -> 4 blocks/CU; grid 1024 = exactly one residency round.
// ---------------------------------------------------------------------------
__global__ __launch_bounds__(256, 4) void flash_kernel(
    const unsigned short* __restrict__ QN, const unsigned short* __restrict__ XkT,
    const unsigned short* __restrict__ Vpv, float* __restrict__ partO,
    float* __restrict__ partML)
{
  __shared__ unsigned short ks[512 * 40] __attribute__((aligned(16)));  // 40 KB
  const int blk = blockIdx.x;
  const int b   = blk >> 9;
  const int qg  = (blk >> 3) & 63;
  const int ksp = blk & 7;
  const int t = threadIdx.x, w = t >> 6;
  const int lane = t & 63, c = lane & 15, g = lane >> 4;
  const int t0 = qg * 64 + w * 16;
  const int gk0 = ksp * 512;

  // ---- cooperative stage: 512 keys x 64B = 32KB -> ks (row stride 40 sh) ----
  {
    const unsigned short* src = XkT + ((size_t)(b * N_TOK + gk0)) * CK;
    #pragma unroll
    for (int r = 0; r < 8; r++) {
      int flat = r * 256 + t;                  // 2048 x 16B units
      int row = flat >> 2, part = flat & 3;    // key row = 64B = 4 units
      *(uint4*)(ks + row * 40 + part * 8) = *(const uint4*)(src + (size_t)flat * 8);
    }
  }
  const bf16x8 qf = *(const bf16x8*)(QN + ((size_t)(b * N_TOK + t0 + c)) * CK + g * 8);
  __syncthreads();

  const unsigned short* vp = Vpv + (size_t)b * 128 * 1024;   // [ch32][32d][32pos]
  float mO = -1e30f, lO = 0.f;                 // merged state
  f32x4 O0 = {}, O1 = {};

  #pragma unroll
  for (int pass = 0; pass < 2; pass++) {
    const int pk = pass * 256;                 // key base within staged slice

    // ---- phase 1: S^T for 256 keys (16 independent MFMAs from LDS) ----
    f32x4 s[4][4];
    #pragma unroll
    for (int it = 0; it < 4; it++)
      #pragma unroll
      for (int nt = 0; nt < 4; nt++) {
        bf16x8 ak = *(const bf16x8*)&ks[(pk + it * 64 + nt * 16 + c) * 40 + g * 8];
        f32x4 z = {};
        s[it][nt] = mfma16(ak, qf, z);         // row=key(g*4+r), col=token(c)
      }

    // ---- phase 2: per-token max ----
    float mx = -1e30f;
    #pragma unroll
    for (int it = 0; it < 4; it++)
      #pragma unroll
      for (int nt = 0; nt < 4; nt++)
        mx = fmaxf(mx, fmaxf(fmaxf(s[it][nt][0], s[it][nt][1]),
                             fmaxf(s[it][nt][2], s[it][nt][3])));
    mx = fmaxf(mx, __shfl_xor(mx, 16));
    mx = fmaxf(mx, __shfl_xor(mx, 32));

    // ---- phase 3: exp, sum, pack P^T (register-resident) ----
    float l = 0.f;
    s16x4 pf[4][4];
    #pragma unroll
    for (int it = 0; it < 4; it++)
      #pragma unroll
      for (int nt = 0; nt < 4; nt++) {
        float p0 = __expf(s[it][nt][0] - mx);
        float p1 = __expf(s[it][nt][1] - mx);
        float p2 = __expf(s[it][nt][2] - mx);
        float p3 = __expf(s[it][nt][3] - mx);
        l += (p0 + p1) + (p2 + p3);
        union { __hip_bfloat162 h2[2]; s16x4 v; } pu;
        pu.h2[0] = __float22bfloat162_rn(make_float2(p0, p1));
        pu.h2[1] = __float22bfloat162_rn(make_float2(p2, p3));
        pf[it][nt] = pu.v;
      }
    l += __shfl_xor(l, 16);
    l += __shfl_xor(l, 32);

    // ---- phase 4: O^T = V^T P^T (16 K=32 MFMAs; 16B coalesced V frags) ----
    f32x4 o0 = {}, o1 = {};
    #pragma unroll
    for (int it = 0; it < 4; it++)
      #pragma unroll
      for (int ntp = 0; ntp < 2; ntp++) {
        const int ch32 = (gk0 + pk + it * 64 + ntp * 32) >> 5;
        const unsigned short* base = vp + (size_t)ch32 * 1024;
        union { s16x4 h[2]; bf16x8 v; } bu;
        bu.h[0] = pf[it][ntp * 2];
        bu.h[1] = pf[it][ntp * 2 + 1];
        bf16x8 a0 = *(const bf16x8*)(base + c * 32 + g * 8);          // d=c
        bf16x8 a1 = *(const bf16x8*)(base + (16 + c) * 32 + g * 8);   // d=16+c
        o0 = mfma16(a0, bu.v, o0);             // row=d(g*4+r), col=token(c)
        o1 = mfma16(a1, bu.v, o1);
      }

    // ---- register merge into running (mO, lO, O) ----
    float mN = fmaxf(mO, mx);
    float fO = __expf(mO - mN), fP = __expf(mx - mN);
    lO = lO * fO + l * fP;
    #pragma unroll
    for (int r = 0; r < 4; r++) {
      O0[r] = O0[r] * fO + o0[r] * fP;
      O1[r] = O1[r] * fO + o1[r] * fP;
    }
    mO = mN;
  }

  // ---- epilogue: per-wave partials straight from registers ----
  float* po = partO + (size_t)blk * 2048 + (w * 16 + c) * 32;
  *(f32x4*)(po + g * 4)      = O0;
  *(f32x4*)(po + 16 + g * 4) = O1;
  if (lane < 16) {
    partML[(size_t)blk * 128 + w * 16 + lane]      = mO;
    partML[(size_t)blk * 128 + 64 + w * 16 + lane] = lO;
  }
}

// ---------------------------------------------------------------------------
// Fused merge + output projection + residual.
// Grid 256 = (b, tt(128 of 32 tok)) x 256 thr (4 waves).
// Phase A: merge 8 ksplit partials for the 32 tokens -> LDS ON tile (bf16).
// Phase B: Y[b][o][t0..t0+32) = W2 @ ON^T + c2 + X  (wave = 64 out rows).
// ---------------------------------------------------------------------------
__global__ __launch_bounds__(256) void oproj_kernel(
    const float* __restrict__ partO, const float* __restrict__ partML,
    const unsigned short* __restrict__ W2bf, const float* __restrict__ c2,
    const float* __restrict__ X, float* __restrict__ Y)
{
  __shared__ unsigned short ons[32][40];
  const int blk = blockIdx.x;
  const int b = blk >> 7, tt = blk & 127;
  const int t = threadIdx.x, w = t >> 6;
  const int lane = t & 63, c = lane & 15, g = lane >> 4;
  const int t0 = tt * 32;

  // ---- phase A: thread = (tok32, ch4-group) ----
  {
    const int tl32 = t >> 3, ch4 = t & 7;
    const int q  = t0 + tl32;
    const int qg = q >> 6, tl = q & 63;
    const int blkbase = (b << 9) + qg * 8;
    float mv[8], lv[8], mM = -1e30f;
    #pragma unroll
    for (int k = 0; k < 8; k++) {
      mv[k] = partML[(size_t)(blkbase + k) * 128 + tl];
      lv[k] = partML[(size_t)(blkbase + k) * 128 + 64 + tl];
      mM = fmaxf(mM, mv[k]);
    }
    float lsum = 0.f, f[8];
    #pragma unroll
    for (int k = 0; k < 8; k++) {
      f[k] = __expf(mv[k] - mM);
      lsum = fmaf(f[k], lv[k], lsum);
    }
    const float inv = 1.0f / lsum;
    float acc[4] = {};
    #pragma unroll
    for (int k = 0; k < 8; k++) {
      float4 v = *(const float4*)(partO + (size_t)(blkbase + k) * 2048 + tl * 32 + ch4 * 4);
      acc[0] = fmaf(f[k], v.x, acc[0]); acc[1] = fmaf(f[k], v.y, acc[1]);
      acc[2] = fmaf(f[k], v.z, acc[2]); acc[3] = fmaf(f[k], v.w, acc[3]);
    }
    ons[tl32][ch4 * 4    ] = f2bf(acc[0] * inv);
    ons[tl32][ch4 * 4 + 1] = f2bf(acc[1] * inv);
    ons[tl32][ch4 * 4 + 2] = f2bf(acc[2] * inv);
    ons[tl32][ch4 * 4 + 3] = f2bf(acc[3] * inv);
  }
  __syncthreads();

  // ---- phase B: wave w owns out rows [w*64, w*64+64) ----
  const int m0 = w * 64;
  bf16x8 bB[2];
  #pragma unroll
  for (int nt = 0; nt < 2; nt++)
    bB[nt] = *(const bf16x8*)&ons[nt * 16 + c][g * 8];
  f32x4 acc[4][2] = {};
  #pragma unroll
  for (int mt = 0; mt < 4; mt++) {
    bf16x8 aW = *(const bf16x8*)(W2bf + (size_t)(m0 + mt * 16 + c) * CK + g * 8);
    acc[mt][0] = mfma16(aW, bB[0], acc[mt][0]);
    acc[mt][1] = mfma16(aW, bB[1], acc[mt][1]);
  }
  #pragma unroll
  for (int mt = 0; mt < 4; mt++)
    #pragma unroll
    for (int r = 0; r < 4; r++) {
      const int row = m0 + mt * 16 + g * 4 + r;
      const float cc = c2[row];
      #pragma unroll
      for (int nt = 0; nt < 2; nt++) {
        size_t idx = ((size_t)(b * CQ + row)) * N_TOK + t0 + nt * 16 + c;
        Y[idx] = acc[mt][nt][r] + cc + X[idx];
      }
    }
}

// ---------------------------------------------------------------------------
extern "C" void kernel_launch(void* const* d_in, const int* in_sizes, int n_in,
                              void* d_out, int out_size, void* d_ws, size_t ws_size,
                              hipStream_t stream) {
  const float* F  = (const float*)d_in[0];   // [2,256,4096]
  const float* Fk = (const float*)d_in[1];   // [2,32,4096]
  const float* Wq = (const float*)d_in[2];
  const float* bq = (const float*)d_in[3];
  const float* Wk = (const float*)d_in[4];
  // bk (d_in[5]) is provably softmax-invariant -> dropped
  const float* Wv = (const float*)d_in[6];
  const float* bv = (const float*)d_in[7];
  const float* Wo = (const float*)d_in[8];
  const float* bo = (const float*)d_in[9];
  float* Y = (float*)d_out;
  char* ws = (char*)d_ws;
  unsigned short* XkT   = (unsigned short*)(ws);                 // 512 KB [2,4096,32]
  unsigned short* Vpv   = (unsigned short*)(ws + (512u << 10));  // 512 KB [2,128,32,32]
  unsigned short* QN    = (unsigned short*)(ws + (1536u << 10)); // 512 KB [2,4096,32]
  unsigned short* Aqkt  = (unsigned short*)(ws + (2048u << 10)); // 16 KB  [32,256]
  unsigned short* W2bf  = (unsigned short*)(ws + (2080u << 10)); // 16 KB  [256,32]
  float*          bqk   = (float*)(ws + (2112u << 10));          // 128 B
  float*          c2    = (float*)(ws + (2116u << 10));          // 1 KB
  float*          partO = (float*)(ws + (4096u << 10));          // 8 MB  [1024][2048]
  float*          partML= (float*)(ws + (16384u << 10));         // 512 KB [1024][128]

  prep_kernel <<<128,  256, 0, stream>>>(Wq, bq, Wk, Wv, bv, Wo, bo, Fk,
                                         Aqkt, bqk, W2bf, c2, Vpv, XkT);
  qproj_kernel<<<256,  128, 0, stream>>>(F, Aqkt, bqk, QN);
  flash_kernel<<<1024, 256, 0, stream>>>(QN, XkT, Vpv, partO, partML);
  oproj_kernel<<<256,  256, 0, stream>>>(partO, partML, W2bf, c2, F, Y);
}